// Round 5
// baseline (157.606 us; speedup 1.0000x reference)
//
#include <hip/hip_runtime.h>

typedef _Float16 f16x8 __attribute__((ext_vector_type(8)));
typedef _Float16 f16x4 __attribute__((ext_vector_type(4)));
typedef float    f32x4 __attribute__((ext_vector_type(4)));

#define B_ 4
#define T_ 4096
#define C_ 768
#define H_ 64
#define BT_ (B_ * T_)
#define SCALE 0.03608439182435161f   // 768^-0.5

// Chunked causal attention decomposition:
// q-tile qt (32 rows) has NT = (qt>>1)+1 kv-tiles (64 wide each).
// Chunks of <=16 tiles; group g = qt/32+1 (1..4) has nc = g chunks.
// Blocks per batch: sum over g of 32*g = 320. Canonical index j in [0,320):
//   g=1: j in [0,32), g=2: [32,96), g=3: [96,192), g=4: [192,320)
//   start(g) = 16*g*(g-1); local = j-start; qt = 32*(g-1)+local/g; c = local%g.

// ---------------------------------------------------------------------------
// W transpose+cast: Wt f16 [192][768] = [Wq^T | Wk^T | Wv^T] rows.
// ---------------------------------------------------------------------------
__global__ __launch_bounds__(256) void wt_cast(
    const float* __restrict__ Wk,
    const float* __restrict__ Wq,
    const float* __restrict__ Wv,
    _Float16* __restrict__ Wt)
{
    __shared__ float Ws[64][192];
    const int tid = threadIdx.x;
    const int k0  = blockIdx.x * 64;
    for (int i = tid; i < 64 * 64; i += 256) {
        const int r = i >> 6, c = i & 63;
        Ws[r][c]       = Wq[(size_t)(k0 + r) * H_ + c];
        Ws[r][64 + c]  = Wk[(size_t)(k0 + r) * H_ + c];
        Ws[r][128 + c] = Wv[(size_t)(k0 + r) * H_ + c];
    }
    __syncthreads();
#pragma unroll
    for (int r = 0; r < 6; ++r) {
        const int idx = tid + r * 256;
        const int n = idx >> 3, c8 = (idx & 7) * 8;
        f16x8 o;
#pragma unroll
        for (int j = 0; j < 8; ++j) o[j] = (_Float16)Ws[c8 + j][n];
        *(f16x8*)&Wt[(size_t)n * C_ + k0 + c8] = o;
    }
}

// ---------------------------------------------------------------------------
// QKV projection as MFMA GEMM: [16384 x 768] * [768 x 192]. (unchanged)
// ---------------------------------------------------------------------------
__global__ __launch_bounds__(256) void qkv_gemm(
    const float* __restrict__ x,
    const _Float16* __restrict__ Wt,
    _Float16* __restrict__ qh,
    _Float16* __restrict__ kh,
    _Float16* __restrict__ vt)
{
    __shared__ _Float16 Ah[32][72];
    __shared__ _Float16 Bh[192][72];

    const int tid  = threadIdx.x;
    const int lane = tid & 63;
    const int w    = tid >> 6;
    const int l15  = lane & 15;
    const int l4   = lane >> 4;
    const int mbase = blockIdx.x * 32;

    f32x4 acc[2][3];
#pragma unroll
    for (int mr = 0; mr < 2; ++mr)
#pragma unroll
        for (int j = 0; j < 3; ++j) acc[mr][j] = (f32x4){0.f, 0.f, 0.f, 0.f};

    for (int k0 = 0; k0 < C_; k0 += 64) {
        __syncthreads();
        {
            const int row = tid >> 3;
            const int cb  = (tid & 7) * 8;
            const float* src = &x[(size_t)(mbase + row) * C_ + k0 + cb];
#pragma unroll
            for (int i = 0; i < 2; ++i) {
                const float4 xv = *(const float4*)(src + i * 4);
                f16x4 h = { (_Float16)xv.x, (_Float16)xv.y,
                            (_Float16)xv.z, (_Float16)xv.w };
                *(f16x4*)&Ah[row][cb + i * 4] = h;
            }
        }
#pragma unroll
        for (int r = 0; r < 6; ++r) {
            const int idx = tid + r * 256;
            const int n = idx >> 3, c8 = (idx & 7) * 8;
            *(f16x8*)&Bh[n][c8] = *(const f16x8*)&Wt[(size_t)n * C_ + k0 + c8];
        }
        __syncthreads();
#pragma unroll
        for (int kk = 0; kk < 2; ++kk) {
            f16x8 af0 = *(const f16x8*)&Ah[l15][kk * 32 + l4 * 8];
            f16x8 af1 = *(const f16x8*)&Ah[16 + l15][kk * 32 + l4 * 8];
#pragma unroll
            for (int j = 0; j < 3; ++j) {
                const f16x8 bf =
                    *(const f16x8*)&Bh[w * 48 + j * 16 + l15][kk * 32 + l4 * 8];
                acc[0][j] = __builtin_amdgcn_mfma_f32_16x16x32_f16(af0, bf, acc[0][j], 0, 0, 0);
                acc[1][j] = __builtin_amdgcn_mfma_f32_16x16x32_f16(af1, bf, acc[1][j], 0, 0, 0);
            }
        }
    }

#pragma unroll
    for (int mr = 0; mr < 2; ++mr) {
        const size_t row0 = mbase + mr * 16 + l4 * 4;
#pragma unroll
        for (int j = 0; j < 3; ++j) {
            const int gcol = w * 48 + j * 16;
            if (gcol < 64) {
                const int h = gcol + l15;
#pragma unroll
                for (int r = 0; r < 4; ++r)
                    qh[(row0 + r) * H_ + h] = (_Float16)(acc[mr][j][r] * SCALE);
            } else if (gcol < 128) {
                const int h = gcol - 64 + l15;
#pragma unroll
                for (int r = 0; r < 4; ++r)
                    kh[(row0 + r) * H_ + h] = (_Float16)acc[mr][j][r];
            } else {
                const int h = gcol - 128 + l15;
                f16x4 o = { (_Float16)acc[mr][j][0], (_Float16)acc[mr][j][1],
                            (_Float16)acc[mr][j][2], (_Float16)acc[mr][j][3] };
                *(f16x4*)&vt[(size_t)h * BT_ + row0] = o;
            }
        }
    }
}

// ---------------------------------------------------------------------------
// Chunked register-direct causal flash attention. One block per
// (batch, q-tile, kv-chunk); 4 waves split the chunk's tiles round-robin
// (<=4 iterations each). nc==1 -> direct out; else partial (O f16, m/l f32).
// ---------------------------------------------------------------------------
__global__ __launch_bounds__(256, 4) void attn(
    const _Float16* __restrict__ qh,
    const _Float16* __restrict__ kh,
    const _Float16* __restrict__ vt,
    float* __restrict__ out,
    _Float16* __restrict__ Op,
    float* __restrict__ Mlp)
{
    __shared__ _Float16 Ps[4][16][72];
    __shared__ float    Om[3][2][16][68];
    __shared__ float    Ml[3][2][2][16];

    const int b = blockIdx.x / 320;
    const int j = 319 - (blockIdx.x - b * 320);   // heavy groups first
    int g, start;
    if (j < 32)       { g = 1; start = 0;   }
    else if (j < 96)  { g = 2; start = 32;  }
    else if (j < 192) { g = 3; start = 96;  }
    else              { g = 4; start = 192; }
    const int local = j - start;
    const int qt = 32 * (g - 1) + local / g;
    const int c  = local - (local / g) * g;
    const int nc = g;
    const int qb = qt << 5;
    const int NT = (qt >> 1) + 1;
    const int tbeg = c * 16;
    const int tend = min(NT, tbeg + 16);

    const int tid = threadIdx.x;
    const int lane = tid & 63;
    const int wid  = tid >> 6;
    const size_t bt0 = (size_t)b * T_;
    const int l15 = lane & 15;
    const int l4  = lane >> 4;

    f16x8 qf[2][2];
#pragma unroll
    for (int qs = 0; qs < 2; ++qs) {
        const size_t qrow = bt0 + qb + qs * 16 + l15;
        qf[qs][0] = *(const f16x8*)&qh[qrow * H_ + l4 * 8];
        qf[qs][1] = *(const f16x8*)&qh[qrow * H_ + 32 + l4 * 8];
    }

    f32x4 O[2][4];
#pragma unroll
    for (int qs = 0; qs < 2; ++qs)
#pragma unroll
        for (int ht = 0; ht < 4; ++ht) O[qs][ht] = (f32x4){0.f, 0.f, 0.f, 0.f};
    float m[2][4], l[2][4];
#pragma unroll
    for (int qs = 0; qs < 2; ++qs)
#pragma unroll
        for (int r = 0; r < 4; ++r) { m[qs][r] = -1e30f; l[qs][r] = 0.f; }

    for (int t = tbeg + wid; t < tend; t += 4) {
        const int kb = t << 6;

        f16x8 kf[4][2];
#pragma unroll
        for (int nt = 0; nt < 4; ++nt)
#pragma unroll
            for (int hf = 0; hf < 2; ++hf)
                kf[nt][hf] = *(const f16x8*)
                    &kh[(bt0 + kb + nt * 16 + l15) * H_ + hf * 32 + l4 * 8];
        f16x8 vf[4][2];
#pragma unroll
        for (int ht = 0; ht < 4; ++ht)
#pragma unroll
            for (int cc = 0; cc < 2; ++cc)
                vf[ht][cc] = *(const f16x8*)
                    &vt[(size_t)(ht * 16 + l15) * BT_ + bt0 + kb + cc * 32 + l4 * 8];

        const bool needMask = (kb + 63 > qb);

#pragma unroll
        for (int qs = 0; qs < 2; ++qs) {
            f32x4 sfr[4];
#pragma unroll
            for (int nt = 0; nt < 4; ++nt) {
                f32x4 z = (f32x4){0.f, 0.f, 0.f, 0.f};
                z = __builtin_amdgcn_mfma_f32_16x16x32_f16(qf[qs][0], kf[nt][0], z, 0, 0, 0);
                sfr[nt] = __builtin_amdgcn_mfma_f32_16x16x32_f16(qf[qs][1], kf[nt][1], z, 0, 0, 0);
            }
            if (needMask) {
                const int qpos = qb + qs * 16 + l4 * 4;
#pragma unroll
                for (int nt = 0; nt < 4; ++nt) {
                    const int cpos = kb + nt * 16 + l15;
#pragma unroll
                    for (int r = 0; r < 4; ++r)
                        if (cpos > qpos + r) sfr[nt][r] = -1e30f;
                }
            }
            float sf[4];
            float p[4][4];
#pragma unroll
            for (int r = 0; r < 4; ++r) {
                float mx = fmaxf(fmaxf(sfr[0][r], sfr[1][r]),
                                 fmaxf(sfr[2][r], sfr[3][r]));
                mx = fmaxf(mx, __shfl_xor(mx, 1));
                mx = fmaxf(mx, __shfl_xor(mx, 2));
                mx = fmaxf(mx, __shfl_xor(mx, 4));
                mx = fmaxf(mx, __shfl_xor(mx, 8));
                const float mn = fmaxf(m[qs][r], mx);
                sf[r] = __expf(m[qs][r] - mn);
                float rs = 0.f;
#pragma unroll
                for (int nt = 0; nt < 4; ++nt) {
                    p[nt][r] = __expf(sfr[nt][r] - mn);
                    rs += p[nt][r];
                }
                rs += __shfl_xor(rs, 1);
                rs += __shfl_xor(rs, 2);
                rs += __shfl_xor(rs, 4);
                rs += __shfl_xor(rs, 8);
                l[qs][r] = l[qs][r] * sf[r] + rs;
                m[qs][r] = mn;
            }
#pragma unroll
            for (int nt = 0; nt < 4; ++nt)
#pragma unroll
                for (int r = 0; r < 4; ++r)
                    Ps[wid][l4 * 4 + r][nt * 16 + l15] = (_Float16)p[nt][r];
#pragma unroll
            for (int ht = 0; ht < 4; ++ht)
#pragma unroll
                for (int r = 0; r < 4; ++r) O[qs][ht][r] *= sf[r];
            const f16x8 pf0 = *(const f16x8*)&Ps[wid][l15][l4 * 8];
            const f16x8 pf1 = *(const f16x8*)&Ps[wid][l15][32 + l4 * 8];
#pragma unroll
            for (int ht = 0; ht < 4; ++ht) {
                O[qs][ht] = __builtin_amdgcn_mfma_f32_16x16x32_f16(pf0, vf[ht][0], O[qs][ht], 0, 0, 0);
                O[qs][ht] = __builtin_amdgcn_mfma_f32_16x16x32_f16(pf1, vf[ht][1], O[qs][ht], 0, 0, 0);
            }
        }
    }

    // ---- intra-block 4-way merge
    __syncthreads();
    if (wid != 0) {
#pragma unroll
        for (int qs = 0; qs < 2; ++qs) {
            if (l15 == 0) {
#pragma unroll
                for (int r = 0; r < 4; ++r) {
                    Ml[wid - 1][qs][0][l4 * 4 + r] = m[qs][r];
                    Ml[wid - 1][qs][1][l4 * 4 + r] = l[qs][r];
                }
            }
#pragma unroll
            for (int ht = 0; ht < 4; ++ht)
#pragma unroll
                for (int r = 0; r < 4; ++r)
                    Om[wid - 1][qs][l4 * 4 + r][ht * 16 + l15] = O[qs][ht][r];
        }
    }
    __syncthreads();
    if (wid == 0) {
        const int slot = b * 320 + j;
#pragma unroll
        for (int qs = 0; qs < 2; ++qs) {
#pragma unroll
            for (int r = 0; r < 4; ++r) {
                const int row = l4 * 4 + r;
                float mf = m[qs][r];
#pragma unroll
                for (int i = 0; i < 3; ++i) mf = fmaxf(mf, Ml[i][qs][0][row]);
                const float a0 = __expf(m[qs][r] - mf);
                float ai[3];
                float denom = l[qs][r] * a0;
#pragma unroll
                for (int i = 0; i < 3; ++i) {
                    ai[i] = __expf(Ml[i][qs][0][row] - mf);
                    denom += Ml[i][qs][1][row] * ai[i];
                }
                if (nc == 1) {
                    const float inv = 1.f / denom;
#pragma unroll
                    for (int ht = 0; ht < 4; ++ht) {
                        float val = O[qs][ht][r] * a0;
#pragma unroll
                        for (int i = 0; i < 3; ++i)
                            val += Om[i][qs][row][ht * 16 + l15] * ai[i];
                        out[(bt0 + qb + qs * 16 + row) * H_ + ht * 16 + l15] = val * inv;
                    }
                } else {
                    const int prow = qs * 16 + row;
#pragma unroll
                    for (int ht = 0; ht < 4; ++ht) {
                        float val = O[qs][ht][r] * a0;
#pragma unroll
                        for (int i = 0; i < 3; ++i)
                            val += Om[i][qs][row][ht * 16 + l15] * ai[i];
                        Op[(size_t)slot * 2048 + prow * 64 + ht * 16 + l15] = (_Float16)val;
                    }
                    if (l15 == 0) {
                        Mlp[(size_t)slot * 64 + prow]      = mf;
                        Mlp[(size_t)slot * 64 + 32 + prow] = denom;
                    }
                }
            }
        }
    }
}

// ---------------------------------------------------------------------------
// Merge partial chunks for q-tiles with nc>=2 (qt >= 32).
// Grid 384 = 4 b x 96 qt. 256 threads: row=tid>>3, 8 cols each.
// ---------------------------------------------------------------------------
__global__ __launch_bounds__(256) void attn_merge(
    const _Float16* __restrict__ Op,
    const float* __restrict__ Mlp,
    float* __restrict__ out)
{
    const int idx = blockIdx.x;
    const int b  = idx / 96;
    const int qt = 32 + (idx - b * 96);
    const int g  = (qt >> 5) + 1;                     // 2..4
    const int jstart = 16 * g * (g - 1) + (qt - 32 * (g - 1)) * g;
    const int slot0  = b * 320 + jstart;

    const int tid  = threadIdx.x;
    const int row  = tid >> 3;
    const int colb = (tid & 7) * 8;

    float mf = -1e30f;
    for (int c = 0; c < g; ++c)
        mf = fmaxf(mf, Mlp[(size_t)(slot0 + c) * 64 + row]);

    float denom = 0.f;
    float acc[8];
#pragma unroll
    for (int jj = 0; jj < 8; ++jj) acc[jj] = 0.f;
    for (int c = 0; c < g; ++c) {
        const float a = __expf(Mlp[(size_t)(slot0 + c) * 64 + row] - mf);
        denom += a * Mlp[(size_t)(slot0 + c) * 64 + 32 + row];
        const f16x8 o = *(const f16x8*)&Op[(size_t)(slot0 + c) * 2048 + row * 64 + colb];
#pragma unroll
        for (int jj = 0; jj < 8; ++jj) acc[jj] += a * (float)o[jj];
    }
    const float inv = 1.f / denom;
    const size_t obase = ((size_t)b * T_ + (qt << 5) + row) * H_ + colb;
#pragma unroll
    for (int jj = 0; jj < 8; ++jj) out[obase + jj] = acc[jj] * inv;
}

extern "C" void kernel_launch(void* const* d_in, const int* in_sizes, int n_in,
                              void* d_out, int out_size, void* d_ws, size_t ws_size,
                              hipStream_t stream) {
    const float* x  = (const float*)d_in[0];
    const float* Wk = (const float*)d_in[1];
    const float* Wq = (const float*)d_in[2];
    const float* Wv = (const float*)d_in[3];
    float* out = (float*)d_out;

    _Float16* qh = (_Float16*)d_ws;                  // [B*T][H] (scaled)
    _Float16* kh = qh + (size_t)BT_ * H_;            // [B*T][H]
    _Float16* vt = kh + (size_t)BT_ * H_;            // [H][B*T]
    _Float16* Wt = vt + (size_t)BT_ * H_;            // [192][768]
    _Float16* Op = Wt + (size_t)192 * C_;            // 1280 slots x [32][64] f16
    float*    Mlp = (float*)(Op + (size_t)1280 * 2048);  // 1280 x (m[32],l[32])

    wt_cast<<<dim3(12), dim3(256), 0, stream>>>(Wk, Wq, Wv, Wt);
    qkv_gemm<<<dim3(512), dim3(256), 0, stream>>>(x, Wt, qh, kh, vt);
    attn<<<dim3(1280), dim3(256), 0, stream>>>(qh, kh, vt, out, Op, Mlp);
    attn_merge<<<dim3(384), dim3(256), 0, stream>>>(Op, Mlp, out);
}

// Round 6
// 83.380 us; speedup vs baseline: 1.8902x; 1.8902x over previous
//
#include <hip/hip_runtime.h>

typedef _Float16 f16x8 __attribute__((ext_vector_type(8)));
typedef _Float16 f16x4 __attribute__((ext_vector_type(4)));
typedef float    f32x4 __attribute__((ext_vector_type(4)));

#define B_ 4
#define T_ 4096
#define C_ 768
#define H_ 64
#define BT_ (B_ * T_)
#define SCALE 0.03608439182435161f   // 768^-0.5

// Chunked causal attention decomposition:
// q-tile qt (32 rows) has NT = (qt>>1)+1 kv-tiles (64 wide each).
// Chunks of <=16 tiles; group g = qt/32+1 (1..4) has nc = g chunks.
// Blocks per batch: sum over g of 32*g = 320. Canonical index j in [0,320):
//   g=1: j in [0,32), g=2: [32,96), g=3: [96,192), g=4: [192,320)
//   start(g) = 16*g*(g-1); local = j-start; qt = 32*(g-1)+local/g; c = local%g.

// ---------------------------------------------------------------------------
// W transpose+cast: Wt f16 [192][768] = [Wq^T | Wk^T | Wv^T] rows.
// ---------------------------------------------------------------------------
__global__ __launch_bounds__(256) void wt_cast(
    const float* __restrict__ Wk,
    const float* __restrict__ Wq,
    const float* __restrict__ Wv,
    _Float16* __restrict__ Wt)
{
    __shared__ float Ws[64][192];
    const int tid = threadIdx.x;
    const int k0  = blockIdx.x * 64;
    for (int i = tid; i < 64 * 64; i += 256) {
        const int r = i >> 6, c = i & 63;
        Ws[r][c]       = Wq[(size_t)(k0 + r) * H_ + c];
        Ws[r][64 + c]  = Wk[(size_t)(k0 + r) * H_ + c];
        Ws[r][128 + c] = Wv[(size_t)(k0 + r) * H_ + c];
    }
    __syncthreads();
#pragma unroll
    for (int r = 0; r < 6; ++r) {
        const int idx = tid + r * 256;
        const int n = idx >> 3, c8 = (idx & 7) * 8;
        f16x8 o;
#pragma unroll
        for (int j = 0; j < 8; ++j) o[j] = (_Float16)Ws[c8 + j][n];
        *(f16x8*)&Wt[(size_t)n * C_ + k0 + c8] = o;
    }
}

// ---------------------------------------------------------------------------
// QKV projection as MFMA GEMM: [16384 x 768] * [768 x 192]. (unchanged)
// ---------------------------------------------------------------------------
__global__ __launch_bounds__(256) void qkv_gemm(
    const float* __restrict__ x,
    const _Float16* __restrict__ Wt,
    _Float16* __restrict__ qh,
    _Float16* __restrict__ kh,
    _Float16* __restrict__ vt)
{
    __shared__ _Float16 Ah[32][72];
    __shared__ _Float16 Bh[192][72];

    const int tid  = threadIdx.x;
    const int lane = tid & 63;
    const int w    = tid >> 6;
    const int l15  = lane & 15;
    const int l4   = lane >> 4;
    const int mbase = blockIdx.x * 32;

    f32x4 acc[2][3];
#pragma unroll
    for (int mr = 0; mr < 2; ++mr)
#pragma unroll
        for (int j = 0; j < 3; ++j) acc[mr][j] = (f32x4){0.f, 0.f, 0.f, 0.f};

    for (int k0 = 0; k0 < C_; k0 += 64) {
        __syncthreads();
        {
            const int row = tid >> 3;
            const int cb  = (tid & 7) * 8;
            const float* src = &x[(size_t)(mbase + row) * C_ + k0 + cb];
#pragma unroll
            for (int i = 0; i < 2; ++i) {
                const float4 xv = *(const float4*)(src + i * 4);
                f16x4 h = { (_Float16)xv.x, (_Float16)xv.y,
                            (_Float16)xv.z, (_Float16)xv.w };
                *(f16x4*)&Ah[row][cb + i * 4] = h;
            }
        }
#pragma unroll
        for (int r = 0; r < 6; ++r) {
            const int idx = tid + r * 256;
            const int n = idx >> 3, c8 = (idx & 7) * 8;
            *(f16x8*)&Bh[n][c8] = *(const f16x8*)&Wt[(size_t)n * C_ + k0 + c8];
        }
        __syncthreads();
#pragma unroll
        for (int kk = 0; kk < 2; ++kk) {
            f16x8 af0 = *(const f16x8*)&Ah[l15][kk * 32 + l4 * 8];
            f16x8 af1 = *(const f16x8*)&Ah[16 + l15][kk * 32 + l4 * 8];
#pragma unroll
            for (int j = 0; j < 3; ++j) {
                const f16x8 bf =
                    *(const f16x8*)&Bh[w * 48 + j * 16 + l15][kk * 32 + l4 * 8];
                acc[0][j] = __builtin_amdgcn_mfma_f32_16x16x32_f16(af0, bf, acc[0][j], 0, 0, 0);
                acc[1][j] = __builtin_amdgcn_mfma_f32_16x16x32_f16(af1, bf, acc[1][j], 0, 0, 0);
            }
        }
    }

#pragma unroll
    for (int mr = 0; mr < 2; ++mr) {
        const size_t row0 = mbase + mr * 16 + l4 * 4;
#pragma unroll
        for (int j = 0; j < 3; ++j) {
            const int gcol = w * 48 + j * 16;
            if (gcol < 64) {
                const int h = gcol + l15;
#pragma unroll
                for (int r = 0; r < 4; ++r)
                    qh[(row0 + r) * H_ + h] = (_Float16)(acc[mr][j][r] * SCALE);
            } else if (gcol < 128) {
                const int h = gcol - 64 + l15;
#pragma unroll
                for (int r = 0; r < 4; ++r)
                    kh[(row0 + r) * H_ + h] = (_Float16)acc[mr][j][r];
            } else {
                const int h = gcol - 128 + l15;
                f16x4 o = { (_Float16)acc[mr][j][0], (_Float16)acc[mr][j][1],
                            (_Float16)acc[mr][j][2], (_Float16)acc[mr][j][3] };
                *(f16x4*)&vt[(size_t)h * BT_ + row0] = o;
            }
        }
    }
}

// ---------------------------------------------------------------------------
// Chunked register-direct causal flash attention. One block per
// (batch, q-tile, kv-chunk); 4 waves split the chunk's tiles round-robin
// (<=4 iterations each). nc==1 -> direct out; else partial (O f16, m/l f32).
// NOTE: launch_bounds min-waves/EU MUST stay 2 — 4 caps VGPRs at 64 and the
// kernel spills ~350 MB/dispatch to scratch (round-5 regression).
// ---------------------------------------------------------------------------
__global__ __launch_bounds__(256, 2) void attn(
    const _Float16* __restrict__ qh,
    const _Float16* __restrict__ kh,
    const _Float16* __restrict__ vt,
    float* __restrict__ out,
    _Float16* __restrict__ Op,
    float* __restrict__ Mlp)
{
    __shared__ _Float16 Ps[4][16][72];
    __shared__ float    Om[3][2][16][68];
    __shared__ float    Ml[3][2][2][16];

    const int b = blockIdx.x / 320;
    const int j = 319 - (blockIdx.x - b * 320);   // heavy groups first
    int g, start;
    if (j < 32)       { g = 1; start = 0;   }
    else if (j < 96)  { g = 2; start = 32;  }
    else if (j < 192) { g = 3; start = 96;  }
    else              { g = 4; start = 192; }
    const int local = j - start;
    const int qt = 32 * (g - 1) + local / g;
    const int c  = local - (local / g) * g;
    const int nc = g;
    const int qb = qt << 5;
    const int NT = (qt >> 1) + 1;
    const int tbeg = c * 16;
    const int tend = min(NT, tbeg + 16);

    const int tid = threadIdx.x;
    const int lane = tid & 63;
    const int wid  = tid >> 6;
    const size_t bt0 = (size_t)b * T_;
    const int l15 = lane & 15;
    const int l4  = lane >> 4;

    f16x8 qf[2][2];
#pragma unroll
    for (int qs = 0; qs < 2; ++qs) {
        const size_t qrow = bt0 + qb + qs * 16 + l15;
        qf[qs][0] = *(const f16x8*)&qh[qrow * H_ + l4 * 8];
        qf[qs][1] = *(const f16x8*)&qh[qrow * H_ + 32 + l4 * 8];
    }

    f32x4 O[2][4];
#pragma unroll
    for (int qs = 0; qs < 2; ++qs)
#pragma unroll
        for (int ht = 0; ht < 4; ++ht) O[qs][ht] = (f32x4){0.f, 0.f, 0.f, 0.f};
    float m[2][4], l[2][4];
#pragma unroll
    for (int qs = 0; qs < 2; ++qs)
#pragma unroll
        for (int r = 0; r < 4; ++r) { m[qs][r] = -1e30f; l[qs][r] = 0.f; }

    for (int t = tbeg + wid; t < tend; t += 4) {
        const int kb = t << 6;

        f16x8 kf[4][2];
#pragma unroll
        for (int nt = 0; nt < 4; ++nt)
#pragma unroll
            for (int hf = 0; hf < 2; ++hf)
                kf[nt][hf] = *(const f16x8*)
                    &kh[(bt0 + kb + nt * 16 + l15) * H_ + hf * 32 + l4 * 8];
        f16x8 vf[4][2];
#pragma unroll
        for (int ht = 0; ht < 4; ++ht)
#pragma unroll
            for (int cc = 0; cc < 2; ++cc)
                vf[ht][cc] = *(const f16x8*)
                    &vt[(size_t)(ht * 16 + l15) * BT_ + bt0 + kb + cc * 32 + l4 * 8];

        const bool needMask = (kb + 63 > qb);

#pragma unroll
        for (int qs = 0; qs < 2; ++qs) {
            f32x4 sfr[4];
#pragma unroll
            for (int nt = 0; nt < 4; ++nt) {
                f32x4 z = (f32x4){0.f, 0.f, 0.f, 0.f};
                z = __builtin_amdgcn_mfma_f32_16x16x32_f16(qf[qs][0], kf[nt][0], z, 0, 0, 0);
                sfr[nt] = __builtin_amdgcn_mfma_f32_16x16x32_f16(qf[qs][1], kf[nt][1], z, 0, 0, 0);
            }
            if (needMask) {
                const int qpos = qb + qs * 16 + l4 * 4;
#pragma unroll
                for (int nt = 0; nt < 4; ++nt) {
                    const int cpos = kb + nt * 16 + l15;
#pragma unroll
                    for (int r = 0; r < 4; ++r)
                        if (cpos > qpos + r) sfr[nt][r] = -1e30f;
                }
            }
            float sf[4];
            float p[4][4];
#pragma unroll
            for (int r = 0; r < 4; ++r) {
                float mx = fmaxf(fmaxf(sfr[0][r], sfr[1][r]),
                                 fmaxf(sfr[2][r], sfr[3][r]));
                mx = fmaxf(mx, __shfl_xor(mx, 1));
                mx = fmaxf(mx, __shfl_xor(mx, 2));
                mx = fmaxf(mx, __shfl_xor(mx, 4));
                mx = fmaxf(mx, __shfl_xor(mx, 8));
                const float mn = fmaxf(m[qs][r], mx);
                sf[r] = __expf(m[qs][r] - mn);
                float rs = 0.f;
#pragma unroll
                for (int nt = 0; nt < 4; ++nt) {
                    p[nt][r] = __expf(sfr[nt][r] - mn);
                    rs += p[nt][r];
                }
                rs += __shfl_xor(rs, 1);
                rs += __shfl_xor(rs, 2);
                rs += __shfl_xor(rs, 4);
                rs += __shfl_xor(rs, 8);
                l[qs][r] = l[qs][r] * sf[r] + rs;
                m[qs][r] = mn;
            }
#pragma unroll
            for (int nt = 0; nt < 4; ++nt)
#pragma unroll
                for (int r = 0; r < 4; ++r)
                    Ps[wid][l4 * 4 + r][nt * 16 + l15] = (_Float16)p[nt][r];
#pragma unroll
            for (int ht = 0; ht < 4; ++ht)
#pragma unroll
                for (int r = 0; r < 4; ++r) O[qs][ht][r] *= sf[r];
            const f16x8 pf0 = *(const f16x8*)&Ps[wid][l15][l4 * 8];
            const f16x8 pf1 = *(const f16x8*)&Ps[wid][l15][32 + l4 * 8];
#pragma unroll
            for (int ht = 0; ht < 4; ++ht) {
                O[qs][ht] = __builtin_amdgcn_mfma_f32_16x16x32_f16(pf0, vf[ht][0], O[qs][ht], 0, 0, 0);
                O[qs][ht] = __builtin_amdgcn_mfma_f32_16x16x32_f16(pf1, vf[ht][1], O[qs][ht], 0, 0, 0);
            }
        }
    }

    // ---- intra-block 4-way merge
    __syncthreads();
    if (wid != 0) {
#pragma unroll
        for (int qs = 0; qs < 2; ++qs) {
            if (l15 == 0) {
#pragma unroll
                for (int r = 0; r < 4; ++r) {
                    Ml[wid - 1][qs][0][l4 * 4 + r] = m[qs][r];
                    Ml[wid - 1][qs][1][l4 * 4 + r] = l[qs][r];
                }
            }
#pragma unroll
            for (int ht = 0; ht < 4; ++ht)
#pragma unroll
                for (int r = 0; r < 4; ++r)
                    Om[wid - 1][qs][l4 * 4 + r][ht * 16 + l15] = O[qs][ht][r];
        }
    }
    __syncthreads();
    if (wid == 0) {
        const int slot = b * 320 + j;
#pragma unroll
        for (int qs = 0; qs < 2; ++qs) {
#pragma unroll
            for (int r = 0; r < 4; ++r) {
                const int row = l4 * 4 + r;
                float mf = m[qs][r];
#pragma unroll
                for (int i = 0; i < 3; ++i) mf = fmaxf(mf, Ml[i][qs][0][row]);
                const float a0 = __expf(m[qs][r] - mf);
                float ai[3];
                float denom = l[qs][r] * a0;
#pragma unroll
                for (int i = 0; i < 3; ++i) {
                    ai[i] = __expf(Ml[i][qs][0][row] - mf);
                    denom += Ml[i][qs][1][row] * ai[i];
                }
                if (nc == 1) {
                    const float inv = 1.f / denom;
#pragma unroll
                    for (int ht = 0; ht < 4; ++ht) {
                        float val = O[qs][ht][r] * a0;
#pragma unroll
                        for (int i = 0; i < 3; ++i)
                            val += Om[i][qs][row][ht * 16 + l15] * ai[i];
                        out[(bt0 + qb + qs * 16 + row) * H_ + ht * 16 + l15] = val * inv;
                    }
                } else {
                    const int prow = qs * 16 + row;
#pragma unroll
                    for (int ht = 0; ht < 4; ++ht) {
                        float val = O[qs][ht][r] * a0;
#pragma unroll
                        for (int i = 0; i < 3; ++i)
                            val += Om[i][qs][row][ht * 16 + l15] * ai[i];
                        Op[(size_t)slot * 2048 + prow * 64 + ht * 16 + l15] = (_Float16)val;
                    }
                    if (l15 == 0) {
                        Mlp[(size_t)slot * 64 + prow]      = mf;
                        Mlp[(size_t)slot * 64 + 32 + prow] = denom;
                    }
                }
            }
        }
    }
}

// ---------------------------------------------------------------------------
// Merge partial chunks for q-tiles with nc>=2 (qt >= 32).
// Grid 384 = 4 b x 96 qt. 256 threads: row=tid>>3, 8 cols each.
// ---------------------------------------------------------------------------
__global__ __launch_bounds__(256) void attn_merge(
    const _Float16* __restrict__ Op,
    const float* __restrict__ Mlp,
    float* __restrict__ out)
{
    const int idx = blockIdx.x;
    const int b  = idx / 96;
    const int qt = 32 + (idx - b * 96);
    const int g  = (qt >> 5) + 1;                     // 2..4
    const int jstart = 16 * g * (g - 1) + (qt - 32 * (g - 1)) * g;
    const int slot0  = b * 320 + jstart;

    const int tid  = threadIdx.x;
    const int row  = tid >> 3;
    const int colb = (tid & 7) * 8;

    float mf = -1e30f;
    for (int c = 0; c < g; ++c)
        mf = fmaxf(mf, Mlp[(size_t)(slot0 + c) * 64 + row]);

    float denom = 0.f;
    float acc[8];
#pragma unroll
    for (int jj = 0; jj < 8; ++jj) acc[jj] = 0.f;
    for (int c = 0; c < g; ++c) {
        const float a = __expf(Mlp[(size_t)(slot0 + c) * 64 + row] - mf);
        denom += a * Mlp[(size_t)(slot0 + c) * 64 + 32 + row];
        const f16x8 o = *(const f16x8*)&Op[(size_t)(slot0 + c) * 2048 + row * 64 + colb];
#pragma unroll
        for (int jj = 0; jj < 8; ++jj) acc[jj] += a * (float)o[jj];
    }
    const float inv = 1.f / denom;
    const size_t obase = ((size_t)b * T_ + (qt << 5) + row) * H_ + colb;
#pragma unroll
    for (int jj = 0; jj < 8; ++jj) out[obase + jj] = acc[jj] * inv;
}

extern "C" void kernel_launch(void* const* d_in, const int* in_sizes, int n_in,
                              void* d_out, int out_size, void* d_ws, size_t ws_size,
                              hipStream_t stream) {
    const float* x  = (const float*)d_in[0];
    const float* Wk = (const float*)d_in[1];
    const float* Wq = (const float*)d_in[2];
    const float* Wv = (const float*)d_in[3];
    float* out = (float*)d_out;

    _Float16* qh = (_Float16*)d_ws;                  // [B*T][H] (scaled)
    _Float16* kh = qh + (size_t)BT_ * H_;            // [B*T][H]
    _Float16* vt = kh + (size_t)BT_ * H_;            // [H][B*T]
    _Float16* Wt = vt + (size_t)BT_ * H_;            // [192][768]
    _Float16* Op = Wt + (size_t)192 * C_;            // 1280 slots x [32][64] f16
    float*    Mlp = (float*)(Op + (size_t)1280 * 2048);  // 1280 x (m[32],l[32])

    wt_cast<<<dim3(12), dim3(256), 0, stream>>>(Wk, Wq, Wv, Wt);
    qkv_gemm<<<dim3(512), dim3(256), 0, stream>>>(x, Wt, qh, kh, vt);
    attn<<<dim3(1280), dim3(256), 0, stream>>>(qh, kh, vt, out, Op, Mlp);
    attn_merge<<<dim3(384), dim3(256), 0, stream>>>(Op, Mlp, out);
}

// Round 7
// 83.193 us; speedup vs baseline: 1.8945x; 1.0023x over previous
//
#include <hip/hip_runtime.h>

typedef _Float16 f16x8 __attribute__((ext_vector_type(8)));
typedef _Float16 f16x4 __attribute__((ext_vector_type(4)));
typedef float    f32x4 __attribute__((ext_vector_type(4)));

#define B_ 4
#define T_ 4096
#define C_ 768
#define H_ 64
#define BT_ (B_ * T_)
#define SCALE 0.03608439182435161f   // 768^-0.5

// V layout: vtt[kv_tile][h][s_local] — 8 KB tiles ([64 h][64 s] f16).
// Rationale: the previous vt[h][B*T] layout put consecutive h-rows 32 KB
// apart; a V-fragment load read 16 lines at 32 KB power-of-2 stride ->
// same-channel serialization in L2/HBM (the round-6 latency mystery).
// Tiled layout keeps every fragment access inside one 8 KB tile.

// ---------------------------------------------------------------------------
// W transpose+cast: Wt f16 [192][768] = [Wq^T | Wk^T | Wv^T] rows.
// ---------------------------------------------------------------------------
__global__ __launch_bounds__(256) void wt_cast(
    const float* __restrict__ Wk,
    const float* __restrict__ Wq,
    const float* __restrict__ Wv,
    _Float16* __restrict__ Wt)
{
    __shared__ float Ws[64][192];
    const int tid = threadIdx.x;
    const int k0  = blockIdx.x * 64;
    for (int i = tid; i < 64 * 64; i += 256) {
        const int r = i >> 6, c = i & 63;
        Ws[r][c]       = Wq[(size_t)(k0 + r) * H_ + c];
        Ws[r][64 + c]  = Wk[(size_t)(k0 + r) * H_ + c];
        Ws[r][128 + c] = Wv[(size_t)(k0 + r) * H_ + c];
    }
    __syncthreads();
#pragma unroll
    for (int r = 0; r < 6; ++r) {
        const int idx = tid + r * 256;
        const int n = idx >> 3, c8 = (idx & 7) * 8;
        f16x8 o;
#pragma unroll
        for (int j = 0; j < 8; ++j) o[j] = (_Float16)Ws[c8 + j][n];
        *(f16x8*)&Wt[(size_t)n * C_ + k0 + c8] = o;
    }
}

// ---------------------------------------------------------------------------
// QKV projection as MFMA GEMM: [16384 x 768] * [768 x 192].
// v epilogue now writes the tiled vtt layout.
// ---------------------------------------------------------------------------
__global__ __launch_bounds__(256) void qkv_gemm(
    const float* __restrict__ x,
    const _Float16* __restrict__ Wt,
    _Float16* __restrict__ qh,
    _Float16* __restrict__ kh,
    _Float16* __restrict__ vtt)
{
    __shared__ _Float16 Ah[32][72];
    __shared__ _Float16 Bh[192][72];

    const int tid  = threadIdx.x;
    const int lane = tid & 63;
    const int w    = tid >> 6;
    const int l15  = lane & 15;
    const int l4   = lane >> 4;
    const int mbase = blockIdx.x * 32;

    f32x4 acc[2][3];
#pragma unroll
    for (int mr = 0; mr < 2; ++mr)
#pragma unroll
        for (int j = 0; j < 3; ++j) acc[mr][j] = (f32x4){0.f, 0.f, 0.f, 0.f};

    for (int k0 = 0; k0 < C_; k0 += 64) {
        __syncthreads();
        {
            const int row = tid >> 3;
            const int cb  = (tid & 7) * 8;
            const float* src = &x[(size_t)(mbase + row) * C_ + k0 + cb];
#pragma unroll
            for (int i = 0; i < 2; ++i) {
                const float4 xv = *(const float4*)(src + i * 4);
                f16x4 h = { (_Float16)xv.x, (_Float16)xv.y,
                            (_Float16)xv.z, (_Float16)xv.w };
                *(f16x4*)&Ah[row][cb + i * 4] = h;
            }
        }
#pragma unroll
        for (int r = 0; r < 6; ++r) {
            const int idx = tid + r * 256;
            const int n = idx >> 3, c8 = (idx & 7) * 8;
            *(f16x8*)&Bh[n][c8] = *(const f16x8*)&Wt[(size_t)n * C_ + k0 + c8];
        }
        __syncthreads();
#pragma unroll
        for (int kk = 0; kk < 2; ++kk) {
            f16x8 af0 = *(const f16x8*)&Ah[l15][kk * 32 + l4 * 8];
            f16x8 af1 = *(const f16x8*)&Ah[16 + l15][kk * 32 + l4 * 8];
#pragma unroll
            for (int j = 0; j < 3; ++j) {
                const f16x8 bf =
                    *(const f16x8*)&Bh[w * 48 + j * 16 + l15][kk * 32 + l4 * 8];
                acc[0][j] = __builtin_amdgcn_mfma_f32_16x16x32_f16(af0, bf, acc[0][j], 0, 0, 0);
                acc[1][j] = __builtin_amdgcn_mfma_f32_16x16x32_f16(af1, bf, acc[1][j], 0, 0, 0);
            }
        }
    }

#pragma unroll
    for (int mr = 0; mr < 2; ++mr) {
        const size_t row0 = mbase + mr * 16 + l4 * 4;
#pragma unroll
        for (int j = 0; j < 3; ++j) {
            const int gcol = w * 48 + j * 16;
            if (gcol < 64) {
                const int h = gcol + l15;
#pragma unroll
                for (int r = 0; r < 4; ++r)
                    qh[(row0 + r) * H_ + h] = (_Float16)(acc[mr][j][r] * SCALE);
            } else if (gcol < 128) {
                const int h = gcol - 64 + l15;
#pragma unroll
                for (int r = 0; r < 4; ++r)
                    kh[(row0 + r) * H_ + h] = (_Float16)acc[mr][j][r];
            } else {
                const int h = gcol - 128 + l15;
                f16x4 o = { (_Float16)acc[mr][j][0], (_Float16)acc[mr][j][1],
                            (_Float16)acc[mr][j][2], (_Float16)acc[mr][j][3] };
                // tiled store: tile = row0/64, within-tile offset h*64 + row0%64
                *(f16x4*)&vtt[((row0 >> 6) << 12) + (h << 6) + (row0 & 63)] = o;
            }
        }
    }
}

// ---------------------------------------------------------------------------
// Chunked register-direct causal flash attention. One block per
// (batch, q-tile, kv-chunk); 4 waves split the chunk's tiles round-robin
// (<=4 iterations each). nc==1 -> direct out; else partial (O f16, m/l f32).
// NOTE: launch_bounds min-waves/EU MUST stay 2 — 4 caps VGPRs at 64 and the
// kernel spills ~350 MB/dispatch to scratch (round-5 regression).
// ---------------------------------------------------------------------------
__global__ __launch_bounds__(256, 2) void attn(
    const _Float16* __restrict__ qh,
    const _Float16* __restrict__ kh,
    const _Float16* __restrict__ vtt,
    float* __restrict__ out,
    _Float16* __restrict__ Op,
    float* __restrict__ Mlp)
{
    __shared__ _Float16 Ps[4][16][72];
    __shared__ float    Om[3][2][16][68];
    __shared__ float    Ml[3][2][2][16];

    const int b = blockIdx.x / 320;
    const int j = 319 - (blockIdx.x - b * 320);   // heavy groups first
    int g, start;
    if (j < 32)       { g = 1; start = 0;   }
    else if (j < 96)  { g = 2; start = 32;  }
    else if (j < 192) { g = 3; start = 96;  }
    else              { g = 4; start = 192; }
    const int local = j - start;
    const int qt = 32 * (g - 1) + local / g;
    const int c  = local - (local / g) * g;
    const int nc = g;
    const int qb = qt << 5;
    const int NT = (qt >> 1) + 1;
    const int tbeg = c * 16;
    const int tend = min(NT, tbeg + 16);

    const int tid = threadIdx.x;
    const int lane = tid & 63;
    const int wid  = tid >> 6;
    const size_t bt0 = (size_t)b * T_;
    const int l15 = lane & 15;
    const int l4  = lane >> 4;

    f16x8 qf[2][2];
#pragma unroll
    for (int qs = 0; qs < 2; ++qs) {
        const size_t qrow = bt0 + qb + qs * 16 + l15;
        qf[qs][0] = *(const f16x8*)&qh[qrow * H_ + l4 * 8];
        qf[qs][1] = *(const f16x8*)&qh[qrow * H_ + 32 + l4 * 8];
    }

    f32x4 O[2][4];
#pragma unroll
    for (int qs = 0; qs < 2; ++qs)
#pragma unroll
        for (int ht = 0; ht < 4; ++ht) O[qs][ht] = (f32x4){0.f, 0.f, 0.f, 0.f};
    float m[2][4], l[2][4];
#pragma unroll
    for (int qs = 0; qs < 2; ++qs)
#pragma unroll
        for (int r = 0; r < 4; ++r) { m[qs][r] = -1e30f; l[qs][r] = 0.f; }

    for (int t = tbeg + wid; t < tend; t += 4) {
        const int kb = t << 6;

        f16x8 kf[4][2];
#pragma unroll
        for (int nt = 0; nt < 4; ++nt)
#pragma unroll
            for (int hf = 0; hf < 2; ++hf)
                kf[nt][hf] = *(const f16x8*)
                    &kh[(bt0 + kb + nt * 16 + l15) * H_ + hf * 32 + l4 * 8];
        // V fragments from the 8 KB tile at (bt0+kb): [h][s_local]
        const size_t vtbase = (size_t)(bt0 + kb) << 6;
        f16x8 vf[4][2];
#pragma unroll
        for (int ht = 0; ht < 4; ++ht)
#pragma unroll
            for (int cc = 0; cc < 2; ++cc)
                vf[ht][cc] = *(const f16x8*)
                    &vtt[vtbase + ((ht * 16 + l15) << 6) + cc * 32 + l4 * 8];

        const bool needMask = (kb + 63 > qb);

#pragma unroll
        for (int qs = 0; qs < 2; ++qs) {
            f32x4 sfr[4];
#pragma unroll
            for (int nt = 0; nt < 4; ++nt) {
                f32x4 z = (f32x4){0.f, 0.f, 0.f, 0.f};
                z = __builtin_amdgcn_mfma_f32_16x16x32_f16(qf[qs][0], kf[nt][0], z, 0, 0, 0);
                sfr[nt] = __builtin_amdgcn_mfma_f32_16x16x32_f16(qf[qs][1], kf[nt][1], z, 0, 0, 0);
            }
            if (needMask) {
                const int qpos = qb + qs * 16 + l4 * 4;
#pragma unroll
                for (int nt = 0; nt < 4; ++nt) {
                    const int cpos = kb + nt * 16 + l15;
#pragma unroll
                    for (int r = 0; r < 4; ++r)
                        if (cpos > qpos + r) sfr[nt][r] = -1e30f;
                }
            }
            float sf[4];
            float p[4][4];
#pragma unroll
            for (int r = 0; r < 4; ++r) {
                float mx = fmaxf(fmaxf(sfr[0][r], sfr[1][r]),
                                 fmaxf(sfr[2][r], sfr[3][r]));
                mx = fmaxf(mx, __shfl_xor(mx, 1));
                mx = fmaxf(mx, __shfl_xor(mx, 2));
                mx = fmaxf(mx, __shfl_xor(mx, 4));
                mx = fmaxf(mx, __shfl_xor(mx, 8));
                const float mn = fmaxf(m[qs][r], mx);
                sf[r] = __expf(m[qs][r] - mn);
                float rs = 0.f;
#pragma unroll
                for (int nt = 0; nt < 4; ++nt) {
                    p[nt][r] = __expf(sfr[nt][r] - mn);
                    rs += p[nt][r];
                }
                rs += __shfl_xor(rs, 1);
                rs += __shfl_xor(rs, 2);
                rs += __shfl_xor(rs, 4);
                rs += __shfl_xor(rs, 8);
                l[qs][r] = l[qs][r] * sf[r] + rs;
                m[qs][r] = mn;
            }
#pragma unroll
            for (int nt = 0; nt < 4; ++nt)
#pragma unroll
                for (int r = 0; r < 4; ++r)
                    Ps[wid][l4 * 4 + r][nt * 16 + l15] = (_Float16)p[nt][r];
#pragma unroll
            for (int ht = 0; ht < 4; ++ht)
#pragma unroll
                for (int r = 0; r < 4; ++r) O[qs][ht][r] *= sf[r];
            const f16x8 pf0 = *(const f16x8*)&Ps[wid][l15][l4 * 8];
            const f16x8 pf1 = *(const f16x8*)&Ps[wid][l15][32 + l4 * 8];
#pragma unroll
            for (int ht = 0; ht < 4; ++ht) {
                O[qs][ht] = __builtin_amdgcn_mfma_f32_16x16x32_f16(pf0, vf[ht][0], O[qs][ht], 0, 0, 0);
                O[qs][ht] = __builtin_amdgcn_mfma_f32_16x16x32_f16(pf1, vf[ht][1], O[qs][ht], 0, 0, 0);
            }
        }
    }

    // ---- intra-block 4-way merge
    __syncthreads();
    if (wid != 0) {
#pragma unroll
        for (int qs = 0; qs < 2; ++qs) {
            if (l15 == 0) {
#pragma unroll
                for (int r = 0; r < 4; ++r) {
                    Ml[wid - 1][qs][0][l4 * 4 + r] = m[qs][r];
                    Ml[wid - 1][qs][1][l4 * 4 + r] = l[qs][r];
                }
            }
#pragma unroll
            for (int ht = 0; ht < 4; ++ht)
#pragma unroll
                for (int r = 0; r < 4; ++r)
                    Om[wid - 1][qs][l4 * 4 + r][ht * 16 + l15] = O[qs][ht][r];
        }
    }
    __syncthreads();
    if (wid == 0) {
        const int slot = b * 320 + j;
#pragma unroll
        for (int qs = 0; qs < 2; ++qs) {
#pragma unroll
            for (int r = 0; r < 4; ++r) {
                const int row = l4 * 4 + r;
                float mf = m[qs][r];
#pragma unroll
                for (int i = 0; i < 3; ++i) mf = fmaxf(mf, Ml[i][qs][0][row]);
                const float a0 = __expf(m[qs][r] - mf);
                float ai[3];
                float denom = l[qs][r] * a0;
#pragma unroll
                for (int i = 0; i < 3; ++i) {
                    ai[i] = __expf(Ml[i][qs][0][row] - mf);
                    denom += Ml[i][qs][1][row] * ai[i];
                }
                if (nc == 1) {
                    const float inv = 1.f / denom;
#pragma unroll
                    for (int ht = 0; ht < 4; ++ht) {
                        float val = O[qs][ht][r] * a0;
#pragma unroll
                        for (int i = 0; i < 3; ++i)
                            val += Om[i][qs][row][ht * 16 + l15] * ai[i];
                        out[(bt0 + qb + qs * 16 + row) * H_ + ht * 16 + l15] = val * inv;
                    }
                } else {
                    const int prow = qs * 16 + row;
#pragma unroll
                    for (int ht = 0; ht < 4; ++ht) {
                        float val = O[qs][ht][r] * a0;
#pragma unroll
                        for (int i = 0; i < 3; ++i)
                            val += Om[i][qs][row][ht * 16 + l15] * ai[i];
                        Op[(size_t)slot * 2048 + prow * 64 + ht * 16 + l15] = (_Float16)val;
                    }
                    if (l15 == 0) {
                        Mlp[(size_t)slot * 64 + prow]      = mf;
                        Mlp[(size_t)slot * 64 + 32 + prow] = denom;
                    }
                }
            }
        }
    }
}

// ---------------------------------------------------------------------------
// Merge partial chunks for q-tiles with nc>=2 (qt >= 32).
// Grid 384 = 4 b x 96 qt. 256 threads: row=tid>>3, 8 cols each.
// ---------------------------------------------------------------------------
__global__ __launch_bounds__(256) void attn_merge(
    const _Float16* __restrict__ Op,
    const float* __restrict__ Mlp,
    float* __restrict__ out)
{
    const int idx = blockIdx.x;
    const int b  = idx / 96;
    const int qt = 32 + (idx - b * 96);
    const int g  = (qt >> 5) + 1;                     // 2..4
    const int jstart = 16 * g * (g - 1) + (qt - 32 * (g - 1)) * g;
    const int slot0  = b * 320 + jstart;

    const int tid  = threadIdx.x;
    const int row  = tid >> 3;
    const int colb = (tid & 7) * 8;

    float mf = -1e30f;
    for (int c = 0; c < g; ++c)
        mf = fmaxf(mf, Mlp[(size_t)(slot0 + c) * 64 + row]);

    float denom = 0.f;
    float acc[8];
#pragma unroll
    for (int jj = 0; jj < 8; ++jj) acc[jj] = 0.f;
    for (int c = 0; c < g; ++c) {
        const float a = __expf(Mlp[(size_t)(slot0 + c) * 64 + row] - mf);
        denom += a * Mlp[(size_t)(slot0 + c) * 64 + 32 + row];
        const f16x8 o = *(const f16x8*)&Op[(size_t)(slot0 + c) * 2048 + row * 64 + colb];
#pragma unroll
        for (int jj = 0; jj < 8; ++jj) acc[jj] += a * (float)o[jj];
    }
    const float inv = 1.f / denom;
    const size_t obase = ((size_t)b * T_ + (qt << 5) + row) * H_ + colb;
#pragma unroll
    for (int jj = 0; jj < 8; ++jj) out[obase + jj] = acc[jj] * inv;
}

extern "C" void kernel_launch(void* const* d_in, const int* in_sizes, int n_in,
                              void* d_out, int out_size, void* d_ws, size_t ws_size,
                              hipStream_t stream) {
    const float* x  = (const float*)d_in[0];
    const float* Wk = (const float*)d_in[1];
    const float* Wq = (const float*)d_in[2];
    const float* Wv = (const float*)d_in[3];
    float* out = (float*)d_out;

    _Float16* qh  = (_Float16*)d_ws;                 // [B*T][H] (scaled)
    _Float16* kh  = qh + (size_t)BT_ * H_;           // [B*T][H]
    _Float16* vtt = kh + (size_t)BT_ * H_;           // [BT/64 tiles][64 h][64 s]
    _Float16* Wt  = vtt + (size_t)BT_ * H_;          // [192][768]
    _Float16* Op  = Wt + (size_t)192 * C_;           // 1280 slots x [32][64] f16
    float*    Mlp = (float*)(Op + (size_t)1280 * 2048);  // 1280 x (m[32],l[32])

    wt_cast<<<dim3(12), dim3(256), 0, stream>>>(Wk, Wq, Wv, Wt);
    qkv_gemm<<<dim3(512), dim3(256), 0, stream>>>(x, Wt, qh, kh, vtt);
    attn<<<dim3(1280), dim3(256), 0, stream>>>(qh, kh, vtt, out, Op, Mlp);
    attn_merge<<<dim3(384), dim3(256), 0, stream>>>(Op, Mlp, out);
}

// Round 8
// 78.106 us; speedup vs baseline: 2.0178x; 1.0651x over previous
//
#include <hip/hip_runtime.h>

typedef _Float16 f16x8 __attribute__((ext_vector_type(8)));
typedef _Float16 f16x4 __attribute__((ext_vector_type(4)));
typedef float    f32x4 __attribute__((ext_vector_type(4)));

#define B_ 4
#define T_ 4096
#define C_ 768
#define H_ 64
#define BT_ (B_ * T_)
#define SCALE 0.03608439182435161f   // 768^-0.5

// ---------------------------------------------------------------------------
// W transpose+cast: Wt f16 [192][768] = [Wq^T | Wk^T | Wv^T] rows.
// ---------------------------------------------------------------------------
__global__ __launch_bounds__(256) void wt_cast(
    const float* __restrict__ Wk,
    const float* __restrict__ Wq,
    const float* __restrict__ Wv,
    _Float16* __restrict__ Wt)
{
    __shared__ float Ws[64][192];
    const int tid = threadIdx.x;
    const int k0  = blockIdx.x * 64;
    for (int i = tid; i < 64 * 64; i += 256) {
        const int r = i >> 6, c = i & 63;
        Ws[r][c]       = Wq[(size_t)(k0 + r) * H_ + c];
        Ws[r][64 + c]  = Wk[(size_t)(k0 + r) * H_ + c];
        Ws[r][128 + c] = Wv[(size_t)(k0 + r) * H_ + c];
    }
    __syncthreads();
#pragma unroll
    for (int r = 0; r < 6; ++r) {
        const int idx = tid + r * 256;
        const int n = idx >> 3, c8 = (idx & 7) * 8;
        f16x8 o;
#pragma unroll
        for (int j = 0; j < 8; ++j) o[j] = (_Float16)Ws[c8 + j][n];
        *(f16x8*)&Wt[(size_t)n * C_ + k0 + c8] = o;
    }
}

// ---------------------------------------------------------------------------
// QKV projection as MFMA GEMM: [16384 x 768] * [768 x 192]. (unchanged)
// ---------------------------------------------------------------------------
__global__ __launch_bounds__(256) void qkv_gemm(
    const float* __restrict__ x,
    const _Float16* __restrict__ Wt,
    _Float16* __restrict__ qh,
    _Float16* __restrict__ kh,
    _Float16* __restrict__ vtt)
{
    __shared__ _Float16 Ah[32][72];
    __shared__ _Float16 Bh[192][72];

    const int tid  = threadIdx.x;
    const int lane = tid & 63;
    const int w    = tid >> 6;
    const int l15  = lane & 15;
    const int l4   = lane >> 4;
    const int mbase = blockIdx.x * 32;

    f32x4 acc[2][3];
#pragma unroll
    for (int mr = 0; mr < 2; ++mr)
#pragma unroll
        for (int j = 0; j < 3; ++j) acc[mr][j] = (f32x4){0.f, 0.f, 0.f, 0.f};

    for (int k0 = 0; k0 < C_; k0 += 64) {
        __syncthreads();
        {
            const int row = tid >> 3;
            const int cb  = (tid & 7) * 8;
            const float* src = &x[(size_t)(mbase + row) * C_ + k0 + cb];
#pragma unroll
            for (int i = 0; i < 2; ++i) {
                const float4 xv = *(const float4*)(src + i * 4);
                f16x4 h = { (_Float16)xv.x, (_Float16)xv.y,
                            (_Float16)xv.z, (_Float16)xv.w };
                *(f16x4*)&Ah[row][cb + i * 4] = h;
            }
        }
#pragma unroll
        for (int r = 0; r < 6; ++r) {
            const int idx = tid + r * 256;
            const int n = idx >> 3, c8 = (idx & 7) * 8;
            *(f16x8*)&Bh[n][c8] = *(const f16x8*)&Wt[(size_t)n * C_ + k0 + c8];
        }
        __syncthreads();
#pragma unroll
        for (int kk = 0; kk < 2; ++kk) {
            f16x8 af0 = *(const f16x8*)&Ah[l15][kk * 32 + l4 * 8];
            f16x8 af1 = *(const f16x8*)&Ah[16 + l15][kk * 32 + l4 * 8];
#pragma unroll
            for (int j = 0; j < 3; ++j) {
                const f16x8 bf =
                    *(const f16x8*)&Bh[w * 48 + j * 16 + l15][kk * 32 + l4 * 8];
                acc[0][j] = __builtin_amdgcn_mfma_f32_16x16x32_f16(af0, bf, acc[0][j], 0, 0, 0);
                acc[1][j] = __builtin_amdgcn_mfma_f32_16x16x32_f16(af1, bf, acc[1][j], 0, 0, 0);
            }
        }
    }

#pragma unroll
    for (int mr = 0; mr < 2; ++mr) {
        const size_t row0 = mbase + mr * 16 + l4 * 4;
#pragma unroll
        for (int j = 0; j < 3; ++j) {
            const int gcol = w * 48 + j * 16;
            if (gcol < 64) {
                const int h = gcol + l15;
#pragma unroll
                for (int r = 0; r < 4; ++r)
                    qh[(row0 + r) * H_ + h] = (_Float16)(acc[mr][j][r] * SCALE);
            } else if (gcol < 128) {
                const int h = gcol - 64 + l15;
#pragma unroll
                for (int r = 0; r < 4; ++r)
                    kh[(row0 + r) * H_ + h] = (_Float16)acc[mr][j][r];
            } else {
                const int h = gcol - 128 + l15;
                f16x4 o = { (_Float16)acc[mr][j][0], (_Float16)acc[mr][j][1],
                            (_Float16)acc[mr][j][2], (_Float16)acc[mr][j][3] };
                *(f16x4*)&vtt[((row0 >> 6) << 12) + (h << 6) + (row0 & 63)] = o;
            }
        }
    }
}

// ---------------------------------------------------------------------------
// Chunked register-direct causal flash attention with SWAPPED-QK softmax:
// S^T = mfma(K_frag, Q_frag) puts a q-row's scores lane-local -> softmax is
// 15 in-lane fmax + 2 shuffles (vs 8 x 4-deep shuffle chains). m/l are
// per-lane scalars (q = lane&15, replicated over lane>>4).
// NOTE: launch_bounds min-waves/EU MUST stay 2 (round-5 spill regression).
// ---------------------------------------------------------------------------
__global__ __launch_bounds__(256, 2) void attn(
    const _Float16* __restrict__ qh,
    const _Float16* __restrict__ kh,
    const _Float16* __restrict__ vtt,
    float* __restrict__ out,
    _Float16* __restrict__ Op,
    float* __restrict__ Mlp)
{
    __shared__ _Float16 Ps[4][16][72];
    __shared__ float    Om[3][2][16][68];
    __shared__ float    Ml[3][2][2][16];

    const int b = blockIdx.x / 320;
    const int j = 319 - (blockIdx.x - b * 320);   // heavy groups first
    int g, start;
    if (j < 32)       { g = 1; start = 0;   }
    else if (j < 96)  { g = 2; start = 32;  }
    else if (j < 192) { g = 3; start = 96;  }
    else              { g = 4; start = 192; }
    const int local = j - start;
    const int qt = 32 * (g - 1) + local / g;
    const int c  = local - (local / g) * g;
    const int nc = g;
    const int qb = qt << 5;
    const int NT = (qt >> 1) + 1;
    const int tbeg = c * 16;
    const int tend = min(NT, tbeg + 16);

    const int tid = threadIdx.x;
    const int lane = tid & 63;
    const int wid  = tid >> 6;
    const size_t bt0 = (size_t)b * T_;
    const int l15 = lane & 15;
    const int l4  = lane >> 4;

    f16x8 qf[2][2];
#pragma unroll
    for (int qs = 0; qs < 2; ++qs) {
        const size_t qrow = bt0 + qb + qs * 16 + l15;
        qf[qs][0] = *(const f16x8*)&qh[qrow * H_ + l4 * 8];
        qf[qs][1] = *(const f16x8*)&qh[qrow * H_ + 32 + l4 * 8];
    }

    f32x4 O[2][4];
#pragma unroll
    for (int qs = 0; qs < 2; ++qs)
#pragma unroll
        for (int ht = 0; ht < 4; ++ht) O[qs][ht] = (f32x4){0.f, 0.f, 0.f, 0.f};
    // per-lane online-softmax state for q-row (qs*16 + l15)
    float m[2] = {-1e30f, -1e30f};
    float l[2] = {0.f, 0.f};

    for (int t = tbeg + wid; t < tend; t += 4) {
        const int kb = t << 6;

        f16x8 kf[4][2];
#pragma unroll
        for (int nt = 0; nt < 4; ++nt)
#pragma unroll
            for (int hf = 0; hf < 2; ++hf)
                kf[nt][hf] = *(const f16x8*)
                    &kh[(bt0 + kb + nt * 16 + l15) * H_ + hf * 32 + l4 * 8];
        const size_t vtbase = (size_t)(bt0 + kb) << 6;
        f16x8 vf[4][2];
#pragma unroll
        for (int ht = 0; ht < 4; ++ht)
#pragma unroll
            for (int cc = 0; cc < 2; ++cc)
                vf[ht][cc] = *(const f16x8*)
                    &vtt[vtbase + ((ht * 16 + l15) << 6) + cc * 32 + l4 * 8];

        const bool needMask = (kb + 63 > qb);

#pragma unroll
        for (int qs = 0; qs < 2; ++qs) {
            // ---- S^T = K Q^T : lane holds S[q=l15][s = nt*16 + l4*4 + r]
            f32x4 st[4];
#pragma unroll
            for (int nt = 0; nt < 4; ++nt) {
                f32x4 z = (f32x4){0.f, 0.f, 0.f, 0.f};
                z = __builtin_amdgcn_mfma_f32_16x16x32_f16(kf[nt][0], qf[qs][0], z, 0, 0, 0);
                st[nt] = __builtin_amdgcn_mfma_f32_16x16x32_f16(kf[nt][1], qf[qs][1], z, 0, 0, 0);
            }
            if (needMask) {
                const int qpos = qb + qs * 16 + l15;
                const int sbase = kb + l4 * 4;
#pragma unroll
                for (int nt = 0; nt < 4; ++nt)
#pragma unroll
                    for (int r = 0; r < 4; ++r)
                        if (sbase + nt * 16 + r > qpos) st[nt][r] = -1e30f;
            }
            // ---- in-lane max, 2-shuffle group reduce
            float mx = st[0][0];
#pragma unroll
            for (int nt = 0; nt < 4; ++nt)
#pragma unroll
                for (int r = 0; r < 4; ++r) mx = fmaxf(mx, st[nt][r]);
            mx = fmaxf(mx, __shfl_xor(mx, 16));
            mx = fmaxf(mx, __shfl_xor(mx, 32));
            const float mn = fmaxf(m[qs], mx);
            const float sf = __expf(m[qs] - mn);
            float rs = 0.f;
#pragma unroll
            for (int nt = 0; nt < 4; ++nt) {
                f16x4 pv;
#pragma unroll
                for (int r = 0; r < 4; ++r) {
                    const float p = __expf(st[nt][r] - mn);
                    rs += p;
                    pv[r] = (_Float16)p;
                }
                *(f16x4*)&Ps[wid][l15][nt * 16 + l4 * 4] = pv;
            }
            rs += __shfl_xor(rs, 16);
            rs += __shfl_xor(rs, 32);
            l[qs] = l[qs] * sf + rs;
            m[qs] = mn;
            // ---- transport sf to O's D-layout rows (q = l4*4+r)
            float sfO[4];
#pragma unroll
            for (int r = 0; r < 4; ++r) sfO[r] = __shfl(sf, l4 * 4 + r);
#pragma unroll
            for (int ht = 0; ht < 4; ++ht)
#pragma unroll
                for (int r = 0; r < 4; ++r) O[qs][ht][r] *= sfO[r];
            const f16x8 pf0 = *(const f16x8*)&Ps[wid][l15][l4 * 8];
            const f16x8 pf1 = *(const f16x8*)&Ps[wid][l15][32 + l4 * 8];
#pragma unroll
            for (int ht = 0; ht < 4; ++ht) {
                O[qs][ht] = __builtin_amdgcn_mfma_f32_16x16x32_f16(pf0, vf[ht][0], O[qs][ht], 0, 0, 0);
                O[qs][ht] = __builtin_amdgcn_mfma_f32_16x16x32_f16(pf1, vf[ht][1], O[qs][ht], 0, 0, 0);
            }
        }
    }

    // ---- convert m/l to D-layout (per-(l4,r) rows) for merge
    float mD[2][4], lD[2][4];
#pragma unroll
    for (int qs = 0; qs < 2; ++qs)
#pragma unroll
        for (int r = 0; r < 4; ++r) {
            mD[qs][r] = __shfl(m[qs], l4 * 4 + r);
            lD[qs][r] = __shfl(l[qs], l4 * 4 + r);
        }

    // ---- intra-block 4-way merge
    __syncthreads();
    if (wid != 0) {
#pragma unroll
        for (int qs = 0; qs < 2; ++qs) {
            if (l15 == 0) {
#pragma unroll
                for (int r = 0; r < 4; ++r) {
                    Ml[wid - 1][qs][0][l4 * 4 + r] = mD[qs][r];
                    Ml[wid - 1][qs][1][l4 * 4 + r] = lD[qs][r];
                }
            }
#pragma unroll
            for (int ht = 0; ht < 4; ++ht)
#pragma unroll
                for (int r = 0; r < 4; ++r)
                    Om[wid - 1][qs][l4 * 4 + r][ht * 16 + l15] = O[qs][ht][r];
        }
    }
    __syncthreads();
    if (wid == 0) {
        const int slot = b * 320 + j;
#pragma unroll
        for (int qs = 0; qs < 2; ++qs) {
#pragma unroll
            for (int r = 0; r < 4; ++r) {
                const int row = l4 * 4 + r;
                float mf = mD[qs][r];
#pragma unroll
                for (int i = 0; i < 3; ++i) mf = fmaxf(mf, Ml[i][qs][0][row]);
                const float a0 = __expf(mD[qs][r] - mf);
                float ai[3];
                float denom = lD[qs][r] * a0;
#pragma unroll
                for (int i = 0; i < 3; ++i) {
                    ai[i] = __expf(Ml[i][qs][0][row] - mf);
                    denom += Ml[i][qs][1][row] * ai[i];
                }
                if (nc == 1) {
                    const float inv = 1.f / denom;
#pragma unroll
                    for (int ht = 0; ht < 4; ++ht) {
                        float val = O[qs][ht][r] * a0;
#pragma unroll
                        for (int i = 0; i < 3; ++i)
                            val += Om[i][qs][row][ht * 16 + l15] * ai[i];
                        out[(bt0 + qb + qs * 16 + row) * H_ + ht * 16 + l15] = val * inv;
                    }
                } else {
                    const int prow = qs * 16 + row;
#pragma unroll
                    for (int ht = 0; ht < 4; ++ht) {
                        float val = O[qs][ht][r] * a0;
#pragma unroll
                        for (int i = 0; i < 3; ++i)
                            val += Om[i][qs][row][ht * 16 + l15] * ai[i];
                        Op[(size_t)slot * 2048 + prow * 64 + ht * 16 + l15] = (_Float16)val;
                    }
                    if (l15 == 0) {
                        Mlp[(size_t)slot * 64 + prow]      = mf;
                        Mlp[(size_t)slot * 64 + 32 + prow] = denom;
                    }
                }
            }
        }
    }
}

// ---------------------------------------------------------------------------
// Merge partial chunks for q-tiles with nc>=2 (qt >= 32).
// ---------------------------------------------------------------------------
__global__ __launch_bounds__(256) void attn_merge(
    const _Float16* __restrict__ Op,
    const float* __restrict__ Mlp,
    float* __restrict__ out)
{
    const int idx = blockIdx.x;
    const int b  = idx / 96;
    const int qt = 32 + (idx - b * 96);
    const int g  = (qt >> 5) + 1;                     // 2..4
    const int jstart = 16 * g * (g - 1) + (qt - 32 * (g - 1)) * g;
    const int slot0  = b * 320 + jstart;

    const int tid  = threadIdx.x;
    const int row  = tid >> 3;
    const int colb = (tid & 7) * 8;

    float mf = -1e30f;
    for (int c = 0; c < g; ++c)
        mf = fmaxf(mf, Mlp[(size_t)(slot0 + c) * 64 + row]);

    float denom = 0.f;
    float acc[8];
#pragma unroll
    for (int jj = 0; jj < 8; ++jj) acc[jj] = 0.f;
    for (int c = 0; c < g; ++c) {
        const float a = __expf(Mlp[(size_t)(slot0 + c) * 64 + row] - mf);
        denom += a * Mlp[(size_t)(slot0 + c) * 64 + 32 + row];
        const f16x8 o = *(const f16x8*)&Op[(size_t)(slot0 + c) * 2048 + row * 64 + colb];
#pragma unroll
        for (int jj = 0; jj < 8; ++jj) acc[jj] += a * (float)o[jj];
    }
    const float inv = 1.f / denom;
    const size_t obase = ((size_t)b * T_ + (qt << 5) + row) * H_ + colb;
#pragma unroll
    for (int jj = 0; jj < 8; ++jj) out[obase + jj] = acc[jj] * inv;
}

extern "C" void kernel_launch(void* const* d_in, const int* in_sizes, int n_in,
                              void* d_out, int out_size, void* d_ws, size_t ws_size,
                              hipStream_t stream) {
    const float* x  = (const float*)d_in[0];
    const float* Wk = (const float*)d_in[1];
    const float* Wq = (const float*)d_in[2];
    const float* Wv = (const float*)d_in[3];
    float* out = (float*)d_out;

    _Float16* qh  = (_Float16*)d_ws;                 // [B*T][H] (scaled)
    _Float16* kh  = qh + (size_t)BT_ * H_;           // [B*T][H]
    _Float16* vtt = kh + (size_t)BT_ * H_;           // [BT/64 tiles][64 h][64 s]
    _Float16* Wt  = vtt + (size_t)BT_ * H_;          // [192][768]
    _Float16* Op  = Wt + (size_t)192 * C_;           // 1280 slots x [32][64] f16
    float*    Mlp = (float*)(Op + (size_t)1280 * 2048);  // 1280 x (m[32],l[32])

    wt_cast<<<dim3(12), dim3(256), 0, stream>>>(Wk, Wq, Wv, Wt);
    qkv_gemm<<<dim3(512), dim3(256), 0, stream>>>(x, Wt, qh, kh, vtt);
    attn<<<dim3(1280), dim3(256), 0, stream>>>(qh, kh, vtt, out, Op, Mlp);
    attn_merge<<<dim3(384), dim3(256), 0, stream>>>(Op, Mlp, out);
}

// Round 9
// 76.677 us; speedup vs baseline: 2.0554x; 1.0186x over previous
//
#include <hip/hip_runtime.h>

typedef _Float16 f16x8 __attribute__((ext_vector_type(8)));
typedef _Float16 f16x4 __attribute__((ext_vector_type(4)));
typedef float    f32x4 __attribute__((ext_vector_type(4)));

#define B_ 4
#define T_ 4096
#define C_ 768
#define H_ 64
#define BT_ (B_ * T_)
#define SCALE 0.03608439182435161f   // 768^-0.5

// ---------------------------------------------------------------------------
// W transpose+cast: Wt f16 [192][768] = [Wq^T | Wk^T | Wv^T] rows.
// ---------------------------------------------------------------------------
__global__ __launch_bounds__(256) void wt_cast(
    const float* __restrict__ Wk,
    const float* __restrict__ Wq,
    const float* __restrict__ Wv,
    _Float16* __restrict__ Wt)
{
    __shared__ float Ws[64][192];
    const int tid = threadIdx.x;
    const int k0  = blockIdx.x * 64;
    for (int i = tid; i < 64 * 64; i += 256) {
        const int r = i >> 6, c = i & 63;
        Ws[r][c]       = Wq[(size_t)(k0 + r) * H_ + c];
        Ws[r][64 + c]  = Wk[(size_t)(k0 + r) * H_ + c];
        Ws[r][128 + c] = Wv[(size_t)(k0 + r) * H_ + c];
    }
    __syncthreads();
#pragma unroll
    for (int r = 0; r < 6; ++r) {
        const int idx = tid + r * 256;
        const int n = idx >> 3, c8 = (idx & 7) * 8;
        f16x8 o;
#pragma unroll
        for (int j = 0; j < 8; ++j) o[j] = (_Float16)Ws[c8 + j][n];
        *(f16x8*)&Wt[(size_t)n * C_ + k0 + c8] = o;
    }
}

// ---------------------------------------------------------------------------
// QKV projection as MFMA GEMM: [16384 x 768] * [768 x 192]. (unchanged)
// ---------------------------------------------------------------------------
__global__ __launch_bounds__(256) void qkv_gemm(
    const float* __restrict__ x,
    const _Float16* __restrict__ Wt,
    _Float16* __restrict__ qh,
    _Float16* __restrict__ kh,
    _Float16* __restrict__ vtt)
{
    __shared__ _Float16 Ah[32][72];
    __shared__ _Float16 Bh[192][72];

    const int tid  = threadIdx.x;
    const int lane = tid & 63;
    const int w    = tid >> 6;
    const int l15  = lane & 15;
    const int l4   = lane >> 4;
    const int mbase = blockIdx.x * 32;

    f32x4 acc[2][3];
#pragma unroll
    for (int mr = 0; mr < 2; ++mr)
#pragma unroll
        for (int j = 0; j < 3; ++j) acc[mr][j] = (f32x4){0.f, 0.f, 0.f, 0.f};

    for (int k0 = 0; k0 < C_; k0 += 64) {
        __syncthreads();
        {
            const int row = tid >> 3;
            const int cb  = (tid & 7) * 8;
            const float* src = &x[(size_t)(mbase + row) * C_ + k0 + cb];
#pragma unroll
            for (int i = 0; i < 2; ++i) {
                const float4 xv = *(const float4*)(src + i * 4);
                f16x4 h = { (_Float16)xv.x, (_Float16)xv.y,
                            (_Float16)xv.z, (_Float16)xv.w };
                *(f16x4*)&Ah[row][cb + i * 4] = h;
            }
        }
#pragma unroll
        for (int r = 0; r < 6; ++r) {
            const int idx = tid + r * 256;
            const int n = idx >> 3, c8 = (idx & 7) * 8;
            *(f16x8*)&Bh[n][c8] = *(const f16x8*)&Wt[(size_t)n * C_ + k0 + c8];
        }
        __syncthreads();
#pragma unroll
        for (int kk = 0; kk < 2; ++kk) {
            f16x8 af0 = *(const f16x8*)&Ah[l15][kk * 32 + l4 * 8];
            f16x8 af1 = *(const f16x8*)&Ah[16 + l15][kk * 32 + l4 * 8];
#pragma unroll
            for (int j = 0; j < 3; ++j) {
                const f16x8 bf =
                    *(const f16x8*)&Bh[w * 48 + j * 16 + l15][kk * 32 + l4 * 8];
                acc[0][j] = __builtin_amdgcn_mfma_f32_16x16x32_f16(af0, bf, acc[0][j], 0, 0, 0);
                acc[1][j] = __builtin_amdgcn_mfma_f32_16x16x32_f16(af1, bf, acc[1][j], 0, 0, 0);
            }
        }
    }

#pragma unroll
    for (int mr = 0; mr < 2; ++mr) {
        const size_t row0 = mbase + mr * 16 + l4 * 4;
#pragma unroll
        for (int j = 0; j < 3; ++j) {
            const int gcol = w * 48 + j * 16;
            if (gcol < 64) {
                const int h = gcol + l15;
#pragma unroll
                for (int r = 0; r < 4; ++r)
                    qh[(row0 + r) * H_ + h] = (_Float16)(acc[mr][j][r] * SCALE);
            } else if (gcol < 128) {
                const int h = gcol - 64 + l15;
#pragma unroll
                for (int r = 0; r < 4; ++r)
                    kh[(row0 + r) * H_ + h] = (_Float16)acc[mr][j][r];
            } else {
                const int h = gcol - 128 + l15;
                f16x4 o = { (_Float16)acc[mr][j][0], (_Float16)acc[mr][j][1],
                            (_Float16)acc[mr][j][2], (_Float16)acc[mr][j][3] };
                *(f16x4*)&vtt[((row0 >> 6) << 12) + (h << 6) + (row0 & 63)] = o;
            }
        }
    }
}

// ---------------------------------------------------------------------------
// Chunked register-direct causal flash attention.
// Swapped-QK softmax (lane-local rows) + ping-pong K prefetch (K for tile
// t+4 is loaded during tile t's compute and kept live across the iteration)
// + cooperative all-wave merge epilogue.
// NOTE: launch_bounds min-waves/EU MUST stay 2 (round-5 spill regression).
// ---------------------------------------------------------------------------
__global__ __launch_bounds__(256, 2) void attn(
    const _Float16* __restrict__ qh,
    const _Float16* __restrict__ kh,
    const _Float16* __restrict__ vtt,
    float* __restrict__ out,
    _Float16* __restrict__ Op,
    float* __restrict__ Mlp)
{
    __shared__ _Float16 Ps[4][16][72];     // P layout shuffle (per wave)
    __shared__ _Float16 Oall[4][32][72];   // per-wave unnormalized O (f16)
    __shared__ float    Mall[4][2][32];    // per-wave m,l per q-row

    const int b = blockIdx.x / 320;
    const int j = 319 - (blockIdx.x - b * 320);   // heavy groups first
    int g, start;
    if (j < 32)       { g = 1; start = 0;   }
    else if (j < 96)  { g = 2; start = 32;  }
    else if (j < 192) { g = 3; start = 96;  }
    else              { g = 4; start = 192; }
    const int local = j - start;
    const int qt = 32 * (g - 1) + local / g;
    const int c  = local - (local / g) * g;
    const int nc = g;
    const int qb = qt << 5;
    const int NT = (qt >> 1) + 1;
    const int tbeg = c * 16;
    const int tend = min(NT, tbeg + 16);

    const int tid = threadIdx.x;
    const int lane = tid & 63;
    const int wid  = tid >> 6;
    const size_t bt0 = (size_t)b * T_;
    const int l15 = lane & 15;
    const int l4  = lane >> 4;

    f16x8 qf[2][2];
#pragma unroll
    for (int qs = 0; qs < 2; ++qs) {
        const size_t qrow = bt0 + qb + qs * 16 + l15;
        qf[qs][0] = *(const f16x8*)&qh[qrow * H_ + l4 * 8];
        qf[qs][1] = *(const f16x8*)&qh[qrow * H_ + 32 + l4 * 8];
    }

    f32x4 O[2][4];
#pragma unroll
    for (int qs = 0; qs < 2; ++qs)
#pragma unroll
        for (int ht = 0; ht < 4; ++ht) O[qs][ht] = (f32x4){0.f, 0.f, 0.f, 0.f};
    // per-lane online-softmax state for q-row (qs*16 + l15)
    float m[2] = {-1e30f, -1e30f};
    float l[2] = {0.f, 0.f};

    int t = tbeg + wid;
    f16x8 kfA[4][2], kfB[4][2];
    if (t < tend) {
        const int kb = t << 6;
#pragma unroll
        for (int nt = 0; nt < 4; ++nt)
#pragma unroll
            for (int hf = 0; hf < 2; ++hf)
                kfA[nt][hf] = *(const f16x8*)
                    &kh[(bt0 + kb + nt * 16 + l15) * H_ + hf * 32 + l4 * 8];
    }

    auto body = [&](f16x8 (&kfc)[4][2], f16x8 (&kfn)[4][2]) {
        const int kb = t << 6;
        // V for this tile — issued FIRST (older than kfn, so PV's wait
        // leaves the kfn prefetch outstanding)
        const size_t vtbase = (size_t)(bt0 + kb) << 6;
        f16x8 vf[4][2];
#pragma unroll
        for (int ht = 0; ht < 4; ++ht)
#pragma unroll
            for (int cc = 0; cc < 2; ++cc)
                vf[ht][cc] = *(const f16x8*)
                    &vtt[vtbase + ((ht * 16 + l15) << 6) + cc * 32 + l4 * 8];
        // prefetch next K tile into kfn (live across iteration boundary)
        const int t2 = t + 4;
        if (t2 < tend) {
            const int kb2 = t2 << 6;
#pragma unroll
            for (int nt = 0; nt < 4; ++nt)
#pragma unroll
                for (int hf = 0; hf < 2; ++hf)
                    kfn[nt][hf] = *(const f16x8*)
                        &kh[(bt0 + kb2 + nt * 16 + l15) * H_ + hf * 32 + l4 * 8];
        }

        const bool needMask = (kb + 63 > qb);
#pragma unroll
        for (int qs = 0; qs < 2; ++qs) {
            // ---- S^T = K Q^T : lane holds S[q=l15][s = nt*16 + l4*4 + r]
            f32x4 st[4];
#pragma unroll
            for (int nt = 0; nt < 4; ++nt) {
                f32x4 z = (f32x4){0.f, 0.f, 0.f, 0.f};
                z = __builtin_amdgcn_mfma_f32_16x16x32_f16(kfc[nt][0], qf[qs][0], z, 0, 0, 0);
                st[nt] = __builtin_amdgcn_mfma_f32_16x16x32_f16(kfc[nt][1], qf[qs][1], z, 0, 0, 0);
            }
            if (needMask) {
                const int qpos = qb + qs * 16 + l15;
                const int sbase = kb + l4 * 4;
#pragma unroll
                for (int nt = 0; nt < 4; ++nt)
#pragma unroll
                    for (int r = 0; r < 4; ++r)
                        if (sbase + nt * 16 + r > qpos) st[nt][r] = -1e30f;
            }
            // ---- in-lane max, 2-shuffle group reduce
            float mx = st[0][0];
#pragma unroll
            for (int nt = 0; nt < 4; ++nt)
#pragma unroll
                for (int r = 0; r < 4; ++r) mx = fmaxf(mx, st[nt][r]);
            mx = fmaxf(mx, __shfl_xor(mx, 16));
            mx = fmaxf(mx, __shfl_xor(mx, 32));
            const float mn = fmaxf(m[qs], mx);
            const float sf = __expf(m[qs] - mn);
            float rs = 0.f;
#pragma unroll
            for (int nt = 0; nt < 4; ++nt) {
                f16x4 pv;
#pragma unroll
                for (int r = 0; r < 4; ++r) {
                    const float p = __expf(st[nt][r] - mn);
                    rs += p;
                    pv[r] = (_Float16)p;
                }
                *(f16x4*)&Ps[wid][l15][nt * 16 + l4 * 4] = pv;
            }
            rs += __shfl_xor(rs, 16);
            rs += __shfl_xor(rs, 32);
            l[qs] = l[qs] * sf + rs;
            m[qs] = mn;
            // ---- transport sf to O's D-layout rows (q = l4*4+r)
            float sfO[4];
#pragma unroll
            for (int r = 0; r < 4; ++r) sfO[r] = __shfl(sf, l4 * 4 + r);
#pragma unroll
            for (int ht = 0; ht < 4; ++ht)
#pragma unroll
                for (int r = 0; r < 4; ++r) O[qs][ht][r] *= sfO[r];
            const f16x8 pf0 = *(const f16x8*)&Ps[wid][l15][l4 * 8];
            const f16x8 pf1 = *(const f16x8*)&Ps[wid][l15][32 + l4 * 8];
#pragma unroll
            for (int ht = 0; ht < 4; ++ht) {
                O[qs][ht] = __builtin_amdgcn_mfma_f32_16x16x32_f16(pf0, vf[ht][0], O[qs][ht], 0, 0, 0);
                O[qs][ht] = __builtin_amdgcn_mfma_f32_16x16x32_f16(pf1, vf[ht][1], O[qs][ht], 0, 0, 0);
            }
        }
    };

    while (t < tend) {
        body(kfA, kfB); t += 4;
        if (t >= tend) break;
        body(kfB, kfA); t += 4;
    }

    // ---- cooperative merge epilogue: all waves publish, all threads merge
#pragma unroll
    for (int qs = 0; qs < 2; ++qs) {
        if (l4 == 0) {
            Mall[wid][0][qs * 16 + l15] = m[qs];
            Mall[wid][1][qs * 16 + l15] = l[qs];
        }
#pragma unroll
        for (int ht = 0; ht < 4; ++ht)
#pragma unroll
            for (int r = 0; r < 4; ++r)
                Oall[wid][qs * 16 + l4 * 4 + r][ht * 16 + l15] = (_Float16)O[qs][ht][r];
    }
    __syncthreads();

    const int prow = tid >> 3;        // 0..31
    const int colb = (tid & 7) * 8;   // 0..56
    float mf = Mall[0][0][prow];
#pragma unroll
    for (int w = 1; w < 4; ++w) mf = fmaxf(mf, Mall[w][0][prow]);
    float denom = 0.f;
    float acc[8];
#pragma unroll
    for (int jj = 0; jj < 8; ++jj) acc[jj] = 0.f;
#pragma unroll
    for (int w = 0; w < 4; ++w) {
        const float a = __expf(Mall[w][0][prow] - mf);
        denom += a * Mall[w][1][prow];
        const f16x8 o = *(const f16x8*)&Oall[w][prow][colb];
#pragma unroll
        for (int jj = 0; jj < 8; ++jj) acc[jj] += a * (float)o[jj];
    }
    if (nc == 1) {
        const float inv = 1.f / denom;
        float4 o0 = { acc[0] * inv, acc[1] * inv, acc[2] * inv, acc[3] * inv };
        float4 o1 = { acc[4] * inv, acc[5] * inv, acc[6] * inv, acc[7] * inv };
        float* dst = &out[(bt0 + qb + prow) * H_ + colb];
        *(float4*)dst = o0;
        *(float4*)(dst + 4) = o1;
    } else {
        const int slot = b * 320 + j;
        f16x8 ov;
#pragma unroll
        for (int jj = 0; jj < 8; ++jj) ov[jj] = (_Float16)acc[jj];
        *(f16x8*)&Op[(size_t)slot * 2048 + prow * 64 + colb] = ov;
        if ((tid & 7) == 0) {
            Mlp[(size_t)slot * 64 + prow]      = mf;
            Mlp[(size_t)slot * 64 + 32 + prow] = denom;
        }
    }
}

// ---------------------------------------------------------------------------
// Merge partial chunks for q-tiles with nc>=2 (qt >= 32).
// ---------------------------------------------------------------------------
__global__ __launch_bounds__(256) void attn_merge(
    const _Float16* __restrict__ Op,
    const float* __restrict__ Mlp,
    float* __restrict__ out)
{
    const int idx = blockIdx.x;
    const int b  = idx / 96;
    const int qt = 32 + (idx - b * 96);
    const int g  = (qt >> 5) + 1;                     // 2..4
    const int jstart = 16 * g * (g - 1) + (qt - 32 * (g - 1)) * g;
    const int slot0  = b * 320 + jstart;

    const int tid  = threadIdx.x;
    const int row  = tid >> 3;
    const int colb = (tid & 7) * 8;

    float mf = -1e30f;
    for (int c = 0; c < g; ++c)
        mf = fmaxf(mf, Mlp[(size_t)(slot0 + c) * 64 + row]);

    float denom = 0.f;
    float acc[8];
#pragma unroll
    for (int jj = 0; jj < 8; ++jj) acc[jj] = 0.f;
    for (int c = 0; c < g; ++c) {
        const float a = __expf(Mlp[(size_t)(slot0 + c) * 64 + row] - mf);
        denom += a * Mlp[(size_t)(slot0 + c) * 64 + 32 + row];
        const f16x8 o = *(const f16x8*)&Op[(size_t)(slot0 + c) * 2048 + row * 64 + colb];
#pragma unroll
        for (int jj = 0; jj < 8; ++jj) acc[jj] += a * (float)o[jj];
    }
    const float inv = 1.f / denom;
    const size_t obase = ((size_t)b * T_ + (qt << 5) + row) * H_ + colb;
#pragma unroll
    for (int jj = 0; jj < 8; ++jj) out[obase + jj] = acc[jj] * inv;
}

extern "C" void kernel_launch(void* const* d_in, const int* in_sizes, int n_in,
                              void* d_out, int out_size, void* d_ws, size_t ws_size,
                              hipStream_t stream) {
    const float* x  = (const float*)d_in[0];
    const float* Wk = (const float*)d_in[1];
    const float* Wq = (const float*)d_in[2];
    const float* Wv = (const float*)d_in[3];
    float* out = (float*)d_out;

    _Float16* qh  = (_Float16*)d_ws;                 // [B*T][H] (scaled)
    _Float16* kh  = qh + (size_t)BT_ * H_;           // [B*T][H]
    _Float16* vtt = kh + (size_t)BT_ * H_;           // [BT/64 tiles][64 h][64 s]
    _Float16* Wt  = vtt + (size_t)BT_ * H_;          // [192][768]
    _Float16* Op  = Wt + (size_t)192 * C_;           // 1280 slots x [32][64] f16
    float*    Mlp = (float*)(Op + (size_t)1280 * 2048);  // 1280 x (m[32],l[32])

    wt_cast<<<dim3(12), dim3(256), 0, stream>>>(Wk, Wq, Wv, Wt);
    qkv_gemm<<<dim3(512), dim3(256), 0, stream>>>(x, Wt, qh, kh, vtt);
    attn<<<dim3(1280), dim3(256), 0, stream>>>(qh, kh, vtt, out, Op, Mlp);
    attn_merge<<<dim3(384), dim3(256), 0, stream>>>(Op, Mlp, out);
}

// Round 10
// 75.546 us; speedup vs baseline: 2.0862x; 1.0150x over previous
//
#include <hip/hip_runtime.h>

typedef _Float16 f16x8 __attribute__((ext_vector_type(8)));
typedef _Float16 f16x4 __attribute__((ext_vector_type(4)));
typedef float    f32x4 __attribute__((ext_vector_type(4)));

#define B_ 4
#define T_ 4096
#define C_ 768
#define H_ 64
#define BT_ (B_ * T_)
#define SCALE 0.03608439182435161f   // 768^-0.5

// ---------------------------------------------------------------------------
// W transpose+cast: Wt f16 [192][768] = [Wq^T | Wk^T | Wv^T] rows.
// ---------------------------------------------------------------------------
__global__ __launch_bounds__(256) void wt_cast(
    const float* __restrict__ Wk,
    const float* __restrict__ Wq,
    const float* __restrict__ Wv,
    _Float16* __restrict__ Wt)
{
    __shared__ float Ws[64][192];
    const int tid = threadIdx.x;
    const int k0  = blockIdx.x * 64;
    for (int i = tid; i < 64 * 64; i += 256) {
        const int r = i >> 6, c = i & 63;
        Ws[r][c]       = Wq[(size_t)(k0 + r) * H_ + c];
        Ws[r][64 + c]  = Wk[(size_t)(k0 + r) * H_ + c];
        Ws[r][128 + c] = Wv[(size_t)(k0 + r) * H_ + c];
    }
    __syncthreads();
#pragma unroll
    for (int r = 0; r < 6; ++r) {
        const int idx = tid + r * 256;
        const int n = idx >> 3, c8 = (idx & 7) * 8;
        f16x8 o;
#pragma unroll
        for (int j = 0; j < 8; ++j) o[j] = (_Float16)Ws[c8 + j][n];
        *(f16x8*)&Wt[(size_t)n * C_ + k0 + c8] = o;
    }
}

// ---------------------------------------------------------------------------
// QKV projection as MFMA GEMM: [16384 x 768] * [768 x 192]. (unchanged)
// ---------------------------------------------------------------------------
__global__ __launch_bounds__(256) void qkv_gemm(
    const float* __restrict__ x,
    const _Float16* __restrict__ Wt,
    _Float16* __restrict__ qh,
    _Float16* __restrict__ kh,
    _Float16* __restrict__ vtt)
{
    __shared__ _Float16 Ah[32][72];
    __shared__ _Float16 Bh[192][72];

    const int tid  = threadIdx.x;
    const int lane = tid & 63;
    const int w    = tid >> 6;
    const int l15  = lane & 15;
    const int l4   = lane >> 4;
    const int mbase = blockIdx.x * 32;

    f32x4 acc[2][3];
#pragma unroll
    for (int mr = 0; mr < 2; ++mr)
#pragma unroll
        for (int j = 0; j < 3; ++j) acc[mr][j] = (f32x4){0.f, 0.f, 0.f, 0.f};

    for (int k0 = 0; k0 < C_; k0 += 64) {
        __syncthreads();
        {
            const int row = tid >> 3;
            const int cb  = (tid & 7) * 8;
            const float* src = &x[(size_t)(mbase + row) * C_ + k0 + cb];
#pragma unroll
            for (int i = 0; i < 2; ++i) {
                const float4 xv = *(const float4*)(src + i * 4);
                f16x4 h = { (_Float16)xv.x, (_Float16)xv.y,
                            (_Float16)xv.z, (_Float16)xv.w };
                *(f16x4*)&Ah[row][cb + i * 4] = h;
            }
        }
#pragma unroll
        for (int r = 0; r < 6; ++r) {
            const int idx = tid + r * 256;
            const int n = idx >> 3, c8 = (idx & 7) * 8;
            *(f16x8*)&Bh[n][c8] = *(const f16x8*)&Wt[(size_t)n * C_ + k0 + c8];
        }
        __syncthreads();
#pragma unroll
        for (int kk = 0; kk < 2; ++kk) {
            f16x8 af0 = *(const f16x8*)&Ah[l15][kk * 32 + l4 * 8];
            f16x8 af1 = *(const f16x8*)&Ah[16 + l15][kk * 32 + l4 * 8];
#pragma unroll
            for (int j = 0; j < 3; ++j) {
                const f16x8 bf =
                    *(const f16x8*)&Bh[w * 48 + j * 16 + l15][kk * 32 + l4 * 8];
                acc[0][j] = __builtin_amdgcn_mfma_f32_16x16x32_f16(af0, bf, acc[0][j], 0, 0, 0);
                acc[1][j] = __builtin_amdgcn_mfma_f32_16x16x32_f16(af1, bf, acc[1][j], 0, 0, 0);
            }
        }
    }

#pragma unroll
    for (int mr = 0; mr < 2; ++mr) {
        const size_t row0 = mbase + mr * 16 + l4 * 4;
#pragma unroll
        for (int j = 0; j < 3; ++j) {
            const int gcol = w * 48 + j * 16;
            if (gcol < 64) {
                const int h = gcol + l15;
#pragma unroll
                for (int r = 0; r < 4; ++r)
                    qh[(row0 + r) * H_ + h] = (_Float16)(acc[mr][j][r] * SCALE);
            } else if (gcol < 128) {
                const int h = gcol - 64 + l15;
#pragma unroll
                for (int r = 0; r < 4; ++r)
                    kh[(row0 + r) * H_ + h] = (_Float16)acc[mr][j][r];
            } else {
                const int h = gcol - 128 + l15;
                f16x4 o = { (_Float16)acc[mr][j][0], (_Float16)acc[mr][j][1],
                            (_Float16)acc[mr][j][2], (_Float16)acc[mr][j][3] };
                *(f16x4*)&vtt[((row0 >> 6) << 12) + (h << 6) + (row0 & 63)] = o;
            }
        }
    }
}

// ---------------------------------------------------------------------------
// Flash attention, cooperative LDS-staged, barrier-pipelined (m97/T14 style).
// Block = 128 q-rows (4 waves x 32, each wave OWNS its rows -> no intra-block
// O merge). All waves share K/V tiles double-buffered in LDS (+8 f16 pad ->
// 2-way banks). Per tile: barrier; issue stage loads(t+1) [pinned early by
// sched_barrier]; compute(t) from LDS; ds_write staged regs -> other buffer
// (vmcnt wait lands HERE, hidden under compute). Causal kv-chunks of <=8
// tiles -> 576 blocks, heavy-first. Swapped-QK lane-local softmax.
// chunk map: group k (=0..7): qt in [4k,4k+4), nc=k+1, start j = 2k(k+1).
// ---------------------------------------------------------------------------
__global__ __launch_bounds__(256, 2) void attn(
    const _Float16* __restrict__ qh,
    const _Float16* __restrict__ kh,
    const _Float16* __restrict__ vtt,
    float* __restrict__ out,
    _Float16* __restrict__ Op,
    float* __restrict__ Mlp)
{
    __shared__ _Float16 Ks[2][64][72];   // [buf][s_local][h]  (+8 pad)
    __shared__ _Float16 Vs[2][64][72];   // [buf][h][s_local]
    __shared__ _Float16 Ps[4][16][72];   // per-wave P layout shuffle

    const int b = blockIdx.x / 144;
    const int j = 143 - (blockIdx.x - b * 144);   // heavy chunks first
    int k = 0;
    while (k < 7 && j >= 2 * (k + 1) * (k + 2)) ++k;
    const int local = j - 2 * k * (k + 1);
    const int qt = 4 * k + local / (k + 1);       // 128-row q-tile id
    const int c  = local - (local / (k + 1)) * (k + 1);
    const int nc = k + 1;
    const int qb = qt << 7;
    const int NT = 2 * qt + 2;                    // kv tiles (64 each)
    const int t0 = c * 8;
    const int t1 = min(NT, t0 + 8);

    const int tid  = threadIdx.x;
    const int lane = tid & 63;
    const int wid  = tid >> 6;
    const int l15  = lane & 15;
    const int l4   = lane >> 4;
    const size_t bt0 = (size_t)b * T_;
    const int qbw = qb + wid * 32;                // wave's 32 q-rows
    const int tmaxw = 2 * qt + (wid >> 1);        // last tile this wave needs

    // Q fragments (q pre-scaled)
    f16x8 qf[2][2];
#pragma unroll
    for (int qs = 0; qs < 2; ++qs) {
        const size_t qrow = bt0 + qbw + qs * 16 + l15;
        qf[qs][0] = *(const f16x8*)&qh[qrow * H_ + l4 * 8];
        qf[qs][1] = *(const f16x8*)&qh[qrow * H_ + 32 + l4 * 8];
    }

    // staging geometry: thread covers rows r0 and r0+32, 16B at col c0b
    const int r0  = tid >> 3;
    const int c0b = (tid & 7) * 8;

    // prologue: stage tile t0 into buffer 0
    {
        const size_t gb = (size_t)(bt0 + (t0 << 6)) * H_;
        *(f16x8*)&Ks[0][r0][c0b]      = *(const f16x8*)&kh[gb + r0 * 64 + c0b];
        *(f16x8*)&Ks[0][r0 + 32][c0b] = *(const f16x8*)&kh[gb + (r0 + 32) * 64 + c0b];
        *(f16x8*)&Vs[0][r0][c0b]      = *(const f16x8*)&vtt[gb + r0 * 64 + c0b];
        *(f16x8*)&Vs[0][r0 + 32][c0b] = *(const f16x8*)&vtt[gb + (r0 + 32) * 64 + c0b];
    }

    f32x4 O[2][4];
#pragma unroll
    for (int qs = 0; qs < 2; ++qs)
#pragma unroll
        for (int ht = 0; ht < 4; ++ht) O[qs][ht] = (f32x4){0.f, 0.f, 0.f, 0.f};
    float m[2] = {-1e30f, -1e30f};
    float l[2] = {0.f, 0.f};

    int cur = 0;
    for (int t = t0; t < t1; ++t) {
        __syncthreads();   // buf[cur] staged & visible; prior reads of buf[cur^1] done

        // ---- issue stage loads for t+1 (wait happens at the ds_write below)
        f16x8 sk0, sk1, sv0, sv1;
        const bool more = (t + 1 < t1);
        if (more) {
            const size_t gb = (size_t)(bt0 + ((t + 1) << 6)) * H_;
            sk0 = *(const f16x8*)&kh[gb + r0 * 64 + c0b];
            sk1 = *(const f16x8*)&kh[gb + (r0 + 32) * 64 + c0b];
            sv0 = *(const f16x8*)&vtt[gb + r0 * 64 + c0b];
            sv1 = *(const f16x8*)&vtt[gb + (r0 + 32) * 64 + c0b];
        }
        __builtin_amdgcn_sched_barrier(0);   // pin load issue before compute

        // ---- compute tile t from buf[cur]
        if (t <= tmaxw) {
            const int kb = t << 6;
            f16x8 kf[4][2], vf[4][2];
#pragma unroll
            for (int nt = 0; nt < 4; ++nt)
#pragma unroll
                for (int hf = 0; hf < 2; ++hf)
                    kf[nt][hf] = *(const f16x8*)&Ks[cur][nt * 16 + l15][hf * 32 + l4 * 8];
#pragma unroll
            for (int ht = 0; ht < 4; ++ht)
#pragma unroll
                for (int cc = 0; cc < 2; ++cc)
                    vf[ht][cc] = *(const f16x8*)&Vs[cur][ht * 16 + l15][cc * 32 + l4 * 8];

            const bool needMask = (kb + 63 > qbw);
#pragma unroll
            for (int qs = 0; qs < 2; ++qs) {
                // S^T = K Q^T : lane holds S[q=l15][s = kb + nt*16 + l4*4 + r]
                f32x4 st[4];
#pragma unroll
                for (int nt = 0; nt < 4; ++nt) {
                    f32x4 z = (f32x4){0.f, 0.f, 0.f, 0.f};
                    z = __builtin_amdgcn_mfma_f32_16x16x32_f16(kf[nt][0], qf[qs][0], z, 0, 0, 0);
                    st[nt] = __builtin_amdgcn_mfma_f32_16x16x32_f16(kf[nt][1], qf[qs][1], z, 0, 0, 0);
                }
                if (needMask) {
                    const int qpos = qbw + qs * 16 + l15;
                    const int sbase = kb + l4 * 4;
#pragma unroll
                    for (int nt = 0; nt < 4; ++nt)
#pragma unroll
                        for (int r = 0; r < 4; ++r)
                            if (sbase + nt * 16 + r > qpos) st[nt][r] = -1e30f;
                }
                // in-lane max + 2-shuffle reduce
                float mx = st[0][0];
#pragma unroll
                for (int nt = 0; nt < 4; ++nt)
#pragma unroll
                    for (int r = 0; r < 4; ++r) mx = fmaxf(mx, st[nt][r]);
                mx = fmaxf(mx, __shfl_xor(mx, 16));
                mx = fmaxf(mx, __shfl_xor(mx, 32));
                const float mn = fmaxf(m[qs], mx);
                const float sf = __expf(m[qs] - mn);
                float rs = 0.f;
#pragma unroll
                for (int nt = 0; nt < 4; ++nt) {
                    f16x4 pv;
#pragma unroll
                    for (int r = 0; r < 4; ++r) {
                        const float p = __expf(st[nt][r] - mn);
                        rs += p;
                        pv[r] = (_Float16)p;
                    }
                    *(f16x4*)&Ps[wid][l15][nt * 16 + l4 * 4] = pv;
                }
                rs += __shfl_xor(rs, 16);
                rs += __shfl_xor(rs, 32);
                l[qs] = l[qs] * sf + rs;
                m[qs] = mn;
                // transport sf to O's D-layout rows (q = l4*4+r)
                float sfO[4];
#pragma unroll
                for (int r = 0; r < 4; ++r) sfO[r] = __shfl(sf, l4 * 4 + r);
#pragma unroll
                for (int ht = 0; ht < 4; ++ht)
#pragma unroll
                    for (int r = 0; r < 4; ++r) O[qs][ht][r] *= sfO[r];
                const f16x8 pf0 = *(const f16x8*)&Ps[wid][l15][l4 * 8];
                const f16x8 pf1 = *(const f16x8*)&Ps[wid][l15][32 + l4 * 8];
#pragma unroll
                for (int ht = 0; ht < 4; ++ht) {
                    O[qs][ht] = __builtin_amdgcn_mfma_f32_16x16x32_f16(pf0, vf[ht][0], O[qs][ht], 0, 0, 0);
                    O[qs][ht] = __builtin_amdgcn_mfma_f32_16x16x32_f16(pf1, vf[ht][1], O[qs][ht], 0, 0, 0);
                }
            }
        }

        // ---- write staged tile into the other buffer (vmcnt waits here)
        if (more) {
            const int nxt = cur ^ 1;
            *(f16x8*)&Ks[nxt][r0][c0b]      = sk0;
            *(f16x8*)&Ks[nxt][r0 + 32][c0b] = sk1;
            *(f16x8*)&Vs[nxt][r0][c0b]      = sv0;
            *(f16x8*)&Vs[nxt][r0 + 32][c0b] = sv1;
        }
        cur ^= 1;
    }

    // ---- epilogue: each wave owns its 32 rows; transport m/l to D-layout
    float mD[2][4], lD[2][4];
#pragma unroll
    for (int qs = 0; qs < 2; ++qs)
#pragma unroll
        for (int r = 0; r < 4; ++r) {
            mD[qs][r] = __shfl(m[qs], l4 * 4 + r);
            lD[qs][r] = __shfl(l[qs], l4 * 4 + r);
        }

    if (nc == 1) {
#pragma unroll
        for (int qs = 0; qs < 2; ++qs)
#pragma unroll
            for (int r = 0; r < 4; ++r) {
                const float inv = 1.f / lD[qs][r];
                const size_t row = bt0 + qbw + qs * 16 + l4 * 4 + r;
#pragma unroll
                for (int ht = 0; ht < 4; ++ht)
                    out[row * H_ + ht * 16 + l15] = O[qs][ht][r] * inv;
            }
    } else {
        const int slot = b * 144 + j;
#pragma unroll
        for (int qs = 0; qs < 2; ++qs) {
#pragma unroll
            for (int r = 0; r < 4; ++r) {
                const int grow = wid * 32 + qs * 16 + l4 * 4 + r;
#pragma unroll
                for (int ht = 0; ht < 4; ++ht)
                    Op[(size_t)slot * 8192 + grow * 64 + ht * 16 + l15] =
                        (_Float16)O[qs][ht][r];
            }
            if (l4 == 0) {
                const int grow = wid * 32 + qs * 16 + l15;
                Mlp[(size_t)slot * 256 + grow]       = m[qs];
                Mlp[(size_t)slot * 256 + 128 + grow] = l[qs];
            }
        }
    }
}

// ---------------------------------------------------------------------------
// Merge partial chunks for 128-row q-tiles with nc>=2 (qt >= 4).
// Grid 112 = 4 b x 28 qt. Threads: row=it*32+(tid>>3), 8 cols each.
// ---------------------------------------------------------------------------
__global__ __launch_bounds__(256) void attn_merge(
    const _Float16* __restrict__ Op,
    const float* __restrict__ Mlp,
    float* __restrict__ out)
{
    const int b  = blockIdx.x / 28;
    const int qt = 4 + (blockIdx.x - b * 28);
    const int k  = qt >> 2;
    const int g  = k + 1;                              // chunks: 2..8
    const int jstart = 2 * k * (k + 1) + (qt - 4 * k) * (k + 1);
    const int slot0  = b * 144 + jstart;

    const int tid  = threadIdx.x;
    const int colb = (tid & 7) * 8;

    for (int it = 0; it < 4; ++it) {
        const int row = it * 32 + (tid >> 3);
        float mf = -1e30f;
        for (int cc = 0; cc < g; ++cc)
            mf = fmaxf(mf, Mlp[(size_t)(slot0 + cc) * 256 + row]);
        float denom = 0.f;
        float acc[8];
#pragma unroll
        for (int jj = 0; jj < 8; ++jj) acc[jj] = 0.f;
        for (int cc = 0; cc < g; ++cc) {
            const float a = __expf(Mlp[(size_t)(slot0 + cc) * 256 + row] - mf);
            denom += a * Mlp[(size_t)(slot0 + cc) * 256 + 128 + row];
            const f16x8 o = *(const f16x8*)&Op[(size_t)(slot0 + cc) * 8192 + row * 64 + colb];
#pragma unroll
            for (int jj = 0; jj < 8; ++jj) acc[jj] += a * (float)o[jj];
        }
        const float inv = 1.f / denom;
        float* dst = &out[((size_t)b * T_ + (qt << 7) + row) * H_ + colb];
        float4 o0 = { acc[0] * inv, acc[1] * inv, acc[2] * inv, acc[3] * inv };
        float4 o1 = { acc[4] * inv, acc[5] * inv, acc[6] * inv, acc[7] * inv };
        *(float4*)dst = o0;
        *(float4*)(dst + 4) = o1;
    }
}

extern "C" void kernel_launch(void* const* d_in, const int* in_sizes, int n_in,
                              void* d_out, int out_size, void* d_ws, size_t ws_size,
                              hipStream_t stream) {
    const float* x  = (const float*)d_in[0];
    const float* Wk = (const float*)d_in[1];
    const float* Wq = (const float*)d_in[2];
    const float* Wv = (const float*)d_in[3];
    float* out = (float*)d_out;

    _Float16* qh  = (_Float16*)d_ws;                 // [B*T][H] (scaled)
    _Float16* kh  = qh + (size_t)BT_ * H_;           // [B*T][H]
    _Float16* vtt = kh + (size_t)BT_ * H_;           // [BT/64 tiles][64 h][64 s]
    _Float16* Wt  = vtt + (size_t)BT_ * H_;          // [192][768]
    _Float16* Op  = Wt + (size_t)192 * C_;           // 576 slots x [128][64] f16
    float*    Mlp = (float*)(Op + (size_t)576 * 8192);   // 576 x (m[128],l[128])

    wt_cast<<<dim3(12), dim3(256), 0, stream>>>(Wk, Wq, Wv, Wt);
    qkv_gemm<<<dim3(512), dim3(256), 0, stream>>>(x, Wt, qh, kh, vtt);
    attn<<<dim3(576), dim3(256), 0, stream>>>(qh, kh, vtt, out, Op, Mlp);
    attn_merge<<<dim3(112), dim3(256), 0, stream>>>(Op, Mlp, out);
}